// Round 1
// baseline (899.201 us; speedup 1.0000x reference)
//
#include <hip/hip_runtime.h>
#include <hip/hip_bf16.h>
#include <math.h>

#define DEV __device__ __forceinline__

constexpr int B  = 8,  N = 16, P = 128, PL = 16;
constexpr int D  = 128, DS = 16, DTR = 8, DFF = 256, EL = 2;
constexpr int L  = N * P + 1;            // 2049
constexpr int BL = B * L;                // 16392
constexpr int CT = 128;                  // scan chunk length
constexpr int NC = (L + CT - 1) / CT;    // 17
constexpr int MT = (BL + 63) / 64;       // 257 row tiles per direction

DEV float sigmoidf_(float x) { return 1.0f / (1.0f + __expf(-x)); }

DEV float wsum(float v) {
#pragma unroll
  for (int m = 32; m; m >>= 1) v += __shfl_xor(v, m, 64);
  return v;
}

// ---------------- patch embed + view concat -> U (B,L,D) ----------------
__global__ __launch_bounds__(256) void k_embed(
    const float* __restrict__ x, const float* __restrict__ view,
    const float* __restrict__ wp_w, const float* __restrict__ wp_b,
    float* __restrict__ U)
{
  int g = blockIdx.x * 256 + threadIdx.x;
  if (g >= BL * D) return;
  int d = g & (D - 1);
  int row = g >> 7;                  // b*L + t
  int b = row / L, t = row % L;
  float acc;
  if (t < N * P) {
    const float* xr = x + ((size_t)b * N * P + t) * PL;
    acc = wp_b[d];
#pragma unroll
    for (int k = 0; k < PL; ++k) acc += xr[k] * wp_w[d * PL + k];
  } else {
    acc = view[b * D + d];
  }
  U[(size_t)row * D + d] = acc;
}

// ---------------- xz = u @ in_w.T  (gather with time reversal) ----------------
// grid: (2*MT, 4); writes XCP (cols<128) and Zb (cols>=128), rows in s-space
__global__ __launch_bounds__(256) void k_xz(
    const float* __restrict__ U, const float* __restrict__ in_w_l,
    float* __restrict__ XCP, float* __restrict__ Zb)
{
  __shared__ float As[64][69];
  __shared__ float Ws[64][69];
  int rdir = blockIdx.x / MT;
  int tile = blockIdx.x % MT;
  int col0 = blockIdx.y * 64;
  int tid  = threadIdx.x;
  const float* Wb = in_w_l + (size_t)rdir * (2 * D) * D;
  int m0 = tile * 64;
  int r0 = (tid >> 4) << 2, c0 = (tid & 15) << 2;
  float acc[4][4] = {};

  for (int kp = 0; kp < 2; ++kp) {
    for (int q = tid; q < 64 * 16; q += 256) {
      int rr = q >> 4, k4 = (q & 15) << 2;
      int m = m0 + rr;
      float4 v = make_float4(0.f, 0.f, 0.f, 0.f);
      if (m < BL) {
        int b = m / L, s = m % L;
        int idx = rdir ? (L - 1 - s) : s;
        v = *(const float4*)(U + ((size_t)b * L + idx) * D + kp * 64 + k4);
      }
      As[rr][k4] = v.x; As[rr][k4 + 1] = v.y; As[rr][k4 + 2] = v.z; As[rr][k4 + 3] = v.w;
      float4 w = *(const float4*)(Wb + (size_t)(col0 + rr) * D + kp * 64 + k4);
      Ws[rr][k4] = w.x; Ws[rr][k4 + 1] = w.y; Ws[rr][k4 + 2] = w.z; Ws[rr][k4 + 3] = w.w;
    }
    __syncthreads();
#pragma unroll 4
    for (int k = 0; k < 64; ++k) {
      float a0 = As[r0][k], a1 = As[r0 + 1][k], a2 = As[r0 + 2][k], a3 = As[r0 + 3][k];
      float b0 = Ws[c0][k], b1 = Ws[c0 + 1][k], b2 = Ws[c0 + 2][k], b3 = Ws[c0 + 3][k];
      acc[0][0] = fmaf(a0, b0, acc[0][0]); acc[0][1] = fmaf(a0, b1, acc[0][1]);
      acc[0][2] = fmaf(a0, b2, acc[0][2]); acc[0][3] = fmaf(a0, b3, acc[0][3]);
      acc[1][0] = fmaf(a1, b0, acc[1][0]); acc[1][1] = fmaf(a1, b1, acc[1][1]);
      acc[1][2] = fmaf(a1, b2, acc[1][2]); acc[1][3] = fmaf(a1, b3, acc[1][3]);
      acc[2][0] = fmaf(a2, b0, acc[2][0]); acc[2][1] = fmaf(a2, b1, acc[2][1]);
      acc[2][2] = fmaf(a2, b2, acc[2][2]); acc[2][3] = fmaf(a2, b3, acc[2][3]);
      acc[3][0] = fmaf(a3, b0, acc[3][0]); acc[3][1] = fmaf(a3, b1, acc[3][1]);
      acc[3][2] = fmaf(a3, b2, acc[3][2]); acc[3][3] = fmaf(a3, b3, acc[3][3]);
    }
    __syncthreads();
  }
#pragma unroll
  for (int i = 0; i < 4; ++i) {
    int m = m0 + r0 + i;
    if (m >= BL) continue;
    size_t base = ((size_t)rdir * BL + m) * D;
#pragma unroll
    for (int j = 0; j < 4; ++j) {
      int col = col0 + c0 + j;
      if (col < D) XCP[base + col] = acc[i][j];
      else         Zb[base + col - D] = acc[i][j];
    }
  }
}

// ---------------- depthwise conv(2) + silu ----------------
__global__ __launch_bounds__(256) void k_conv(
    const float* __restrict__ XCP, const float* __restrict__ conv_w_l,
    const float* __restrict__ conv_b_l, float* __restrict__ XCC)
{
  int g = blockIdx.x * 256 + threadIdx.x;      // 2*BL*D
  if (g >= 2 * BL * D) return;
  int d = g & 127;
  int row = g >> 7;
  int rdir = row / BL;
  int s = row % L;
  const float* cw = conv_w_l + rdir * D * 2;
  float cur  = XCP[(size_t)row * D + d];
  float prev = (s > 0) ? XCP[((size_t)row - 1) * D + d] : 0.f;
  float v = prev * cw[2 * d] + cur * cw[2 * d + 1] + conv_b_l[rdir * D + d];
  XCC[(size_t)g] = v * sigmoidf_(v);
}

// ---------------- dbc = xcc @ xproj_w.T  -> DBC8 (cols<8), BC (cols 8..39) ----------------
__global__ __launch_bounds__(256) void k_xproj(
    const float* __restrict__ XCC, const float* __restrict__ xproj_w_l,
    float* __restrict__ DBC8, float* __restrict__ BCb)
{
  __shared__ float As[64][69];
  __shared__ float Ws[64][69];
  int rdir = blockIdx.x / MT;
  int tile = blockIdx.x % MT;
  int tid  = threadIdx.x;
  const float* Wb = xproj_w_l + (size_t)rdir * (DTR + 2 * DS) * D;
  int m0 = tile * 64;
  int r0 = (tid >> 4) << 2, c0 = (tid & 15) << 2;
  float acc[4][4] = {};

  for (int kp = 0; kp < 2; ++kp) {
    for (int q = tid; q < 64 * 16; q += 256) {
      int rr = q >> 4, k4 = (q & 15) << 2;
      int m = m0 + rr;
      float4 v = make_float4(0.f, 0.f, 0.f, 0.f);
      if (m < BL) v = *(const float4*)(XCC + ((size_t)rdir * BL + m) * D + kp * 64 + k4);
      As[rr][k4] = v.x; As[rr][k4 + 1] = v.y; As[rr][k4 + 2] = v.z; As[rr][k4 + 3] = v.w;
      float4 w = make_float4(0.f, 0.f, 0.f, 0.f);
      if (rr < DTR + 2 * DS) w = *(const float4*)(Wb + (size_t)rr * D + kp * 64 + k4);
      Ws[rr][k4] = w.x; Ws[rr][k4 + 1] = w.y; Ws[rr][k4 + 2] = w.z; Ws[rr][k4 + 3] = w.w;
    }
    __syncthreads();
#pragma unroll 4
    for (int k = 0; k < 64; ++k) {
      float a0 = As[r0][k], a1 = As[r0 + 1][k], a2 = As[r0 + 2][k], a3 = As[r0 + 3][k];
      float b0 = Ws[c0][k], b1 = Ws[c0 + 1][k], b2 = Ws[c0 + 2][k], b3 = Ws[c0 + 3][k];
      acc[0][0] = fmaf(a0, b0, acc[0][0]); acc[0][1] = fmaf(a0, b1, acc[0][1]);
      acc[0][2] = fmaf(a0, b2, acc[0][2]); acc[0][3] = fmaf(a0, b3, acc[0][3]);
      acc[1][0] = fmaf(a1, b0, acc[1][0]); acc[1][1] = fmaf(a1, b1, acc[1][1]);
      acc[1][2] = fmaf(a1, b2, acc[1][2]); acc[1][3] = fmaf(a1, b3, acc[1][3]);
      acc[2][0] = fmaf(a2, b0, acc[2][0]); acc[2][1] = fmaf(a2, b1, acc[2][1]);
      acc[2][2] = fmaf(a2, b2, acc[2][2]); acc[2][3] = fmaf(a2, b3, acc[2][3]);
      acc[3][0] = fmaf(a3, b0, acc[3][0]); acc[3][1] = fmaf(a3, b1, acc[3][1]);
      acc[3][2] = fmaf(a3, b2, acc[3][2]); acc[3][3] = fmaf(a3, b3, acc[3][3]);
    }
    __syncthreads();
  }
#pragma unroll
  for (int i = 0; i < 4; ++i) {
    int m = m0 + r0 + i;
    if (m >= BL) continue;
    size_t rowi = (size_t)rdir * BL + m;
#pragma unroll
    for (int j = 0; j < 4; ++j) {
      int col = c0 + j;
      if (col < DTR) DBC8[rowi * 8 + col] = acc[i][j];
      else if (col < DTR + 2 * DS) BCb[rowi * 32 + (col - DTR)] = acc[i][j];
    }
  }
}

// ---------------- dt = softplus(dbc8 @ dt_w.T + dt_b) ----------------
__global__ __launch_bounds__(256) void k_dt(
    const float* __restrict__ DBC8, const float* __restrict__ dt_w_l,
    const float* __restrict__ dt_b_l, float* __restrict__ DT)
{
  int g = blockIdx.x * 256 + threadIdx.x;    // 2*BL*D
  if (g >= 2 * BL * D) return;
  int d = g & 127;
  int row = g >> 7;
  int rdir = row / BL;
  const float* db = DBC8 + (size_t)row * 8;
  const float* dw = dt_w_l + (size_t)rdir * D * DTR + d * DTR;
  float a = dt_b_l[rdir * D + d];
#pragma unroll
  for (int j = 0; j < DTR; ++j) a += db[j] * dw[j];
  DT[(size_t)g] = (a > 20.f) ? a : log1pf(__expf(a));
}

// ---------------- scan phase A: per-chunk local end state + sum(dt) ----------------
__global__ __launch_bounds__(128) void k_scanA(
    const float* __restrict__ DT, const float* __restrict__ XCC,
    const float* __restrict__ BCb, const float* __restrict__ Alog_l,
    float* __restrict__ HC, float* __restrict__ DTS)
{
  __shared__ float Bs[CT][DS];
  int blk = blockIdx.x;                 // (rdir*B+b)*NC + c
  int c  = blk % NC;
  int rb = blk / NC;
  int rdir = rb / B;
  int d = threadIdx.x;
  int s0 = c * CT;
  int cnt = min(CT, L - s0);
  size_t rowbase = (size_t)rb * L + s0;
  for (int q = d; q < cnt * DS; q += 128)
    Bs[q >> 4][q & 15] = BCb[(rowbase + (q >> 4)) * 32 + (q & 15)];
  float An[DS];
  const float* Ab = Alog_l + (size_t)rdir * D * DS + (size_t)d * DS;
#pragma unroll
  for (int n = 0; n < DS; ++n) An[n] = -__expf(Ab[n]);
  __syncthreads();
  float h[DS];
#pragma unroll
  for (int n = 0; n < DS; ++n) h[n] = 0.f;
  float dts = 0.f;
  for (int ss = 0; ss < cnt; ++ss) {
    size_t ro = (rowbase + ss) * D + d;
    float dt = DT[ro];
    float xc = XCC[ro];
    dts += dt;
    float e = dt * xc;
#pragma unroll
    for (int n = 0; n < DS; ++n)
      h[n] = __expf(dt * An[n]) * h[n] + e * Bs[ss][n];
  }
  float* hp = HC + ((size_t)blk * D + d) * DS;
#pragma unroll
  for (int n = 0; n < DS; ++n) hp[n] = h[n];
  DTS[(size_t)blk * D + d] = dts;
}

// ---------------- scan phase B: propagate chunk boundary states ----------------
__global__ __launch_bounds__(128) void k_scanB(
    const float* __restrict__ HC, const float* __restrict__ DTS,
    const float* __restrict__ Alog_l, float* __restrict__ HIN)
{
  int rb = blockIdx.x;                  // 2*B
  int rdir = rb / B;
  int d = threadIdx.x;
  float An[DS];
  const float* Ab = Alog_l + (size_t)rdir * D * DS + (size_t)d * DS;
#pragma unroll
  for (int n = 0; n < DS; ++n) An[n] = -__expf(Ab[n]);
  float h[DS];
#pragma unroll
  for (int n = 0; n < DS; ++n) h[n] = 0.f;
  for (int c = 0; c < NC; ++c) {
    size_t idx = ((size_t)(rb * NC + c) * D + d) * DS;
    float* hin = HIN + idx;
#pragma unroll
    for (int n = 0; n < DS; ++n) hin[n] = h[n];
    float dts = DTS[(size_t)(rb * NC + c) * D + d];
    const float* hc = HC + idx;
#pragma unroll
    for (int n = 0; n < DS; ++n)
      h[n] = __expf(dts * An[n]) * h[n] + hc[n];
  }
}

// ---------------- scan phase C: full scan seeded with h_in, emit y (t-space) ----------------
__global__ __launch_bounds__(128) void k_scanC(
    const float* __restrict__ DT, const float* __restrict__ XCC,
    const float* __restrict__ BCb, const float* __restrict__ Zb,
    const float* __restrict__ HIN, const float* __restrict__ Alog_l,
    const float* __restrict__ Dp_l, float* __restrict__ YM)
{
  __shared__ float Bs[CT][DS];
  __shared__ float Cs[CT][DS];
  int blk = blockIdx.x;
  int c  = blk % NC;
  int rb = blk / NC;
  int rdir = rb / B;
  int b = rb % B;
  int d = threadIdx.x;
  int s0 = c * CT;
  int cnt = min(CT, L - s0);
  size_t rowbase = (size_t)rb * L + s0;
  for (int q = d; q < cnt * 2 * DS; q += 128) {
    int ss = q >> 5, j = q & 31;
    float vv = BCb[(rowbase + ss) * 32 + j];
    if (j < DS) Bs[ss][j] = vv; else Cs[ss][j - DS] = vv;
  }
  float An[DS];
  const float* Ab = Alog_l + (size_t)rdir * D * DS + (size_t)d * DS;
#pragma unroll
  for (int n = 0; n < DS; ++n) An[n] = -__expf(Ab[n]);
  float h[DS];
  const float* hin = HIN + ((size_t)blk * D + d) * DS;
#pragma unroll
  for (int n = 0; n < DS; ++n) h[n] = hin[n];
  float Dpv = Dp_l[rdir * D + d];
  __syncthreads();
  for (int ss = 0; ss < cnt; ++ss) {
    size_t ro = (rowbase + ss) * D + d;
    float dt = DT[ro], xc = XCC[ro];
    float e = dt * xc;
    float y = 0.f;
#pragma unroll
    for (int n = 0; n < DS; ++n) {
      h[n] = __expf(dt * An[n]) * h[n] + e * Bs[ss][n];
      y += h[n] * Cs[ss][n];
    }
    y += xc * Dpv;
    float z = Zb[ro];
    y *= z * sigmoidf_(z);
    int s = s0 + ss;
    int tt = rdir ? (L - 1 - s) : s;
    YM[((size_t)rdir * BL + (size_t)b * L + tt) * D + d] = y;
  }
}

// ---------------- out-proj both dirs, accumulate into U ----------------
__global__ __launch_bounds__(256) void k_outproj(
    const float* __restrict__ YM, const float* __restrict__ out_w_l,
    float* __restrict__ U)
{
  __shared__ float As[64][69];
  __shared__ float Ws[64][69];
  int tile = blockIdx.x;
  int col0 = blockIdx.y * 64;
  int tid  = threadIdx.x;
  int m0 = tile * 64;
  int r0 = (tid >> 4) << 2, c0 = (tid & 15) << 2;
  float acc[4][4] = {};
  for (int dir = 0; dir < 2; ++dir) {
    const float* Wb = out_w_l + (size_t)dir * D * D;
    const float* Abase = YM + (size_t)dir * BL * D;
    for (int kp = 0; kp < 2; ++kp) {
      for (int q = tid; q < 64 * 16; q += 256) {
        int rr = q >> 4, k4 = (q & 15) << 2;
        int m = m0 + rr;
        float4 v = make_float4(0.f, 0.f, 0.f, 0.f);
        if (m < BL) v = *(const float4*)(Abase + (size_t)m * D + kp * 64 + k4);
        As[rr][k4] = v.x; As[rr][k4 + 1] = v.y; As[rr][k4 + 2] = v.z; As[rr][k4 + 3] = v.w;
        float4 w = *(const float4*)(Wb + (size_t)(col0 + rr) * D + kp * 64 + k4);
        Ws[rr][k4] = w.x; Ws[rr][k4 + 1] = w.y; Ws[rr][k4 + 2] = w.z; Ws[rr][k4 + 3] = w.w;
      }
      __syncthreads();
#pragma unroll 4
      for (int k = 0; k < 64; ++k) {
        float a0 = As[r0][k], a1 = As[r0 + 1][k], a2 = As[r0 + 2][k], a3 = As[r0 + 3][k];
        float b0 = Ws[c0][k], b1 = Ws[c0 + 1][k], b2 = Ws[c0 + 2][k], b3 = Ws[c0 + 3][k];
        acc[0][0] = fmaf(a0, b0, acc[0][0]); acc[0][1] = fmaf(a0, b1, acc[0][1]);
        acc[0][2] = fmaf(a0, b2, acc[0][2]); acc[0][3] = fmaf(a0, b3, acc[0][3]);
        acc[1][0] = fmaf(a1, b0, acc[1][0]); acc[1][1] = fmaf(a1, b1, acc[1][1]);
        acc[1][2] = fmaf(a1, b2, acc[1][2]); acc[1][3] = fmaf(a1, b3, acc[1][3]);
        acc[2][0] = fmaf(a2, b0, acc[2][0]); acc[2][1] = fmaf(a2, b1, acc[2][1]);
        acc[2][2] = fmaf(a2, b2, acc[2][2]); acc[2][3] = fmaf(a2, b3, acc[2][3]);
        acc[3][0] = fmaf(a3, b0, acc[3][0]); acc[3][1] = fmaf(a3, b1, acc[3][1]);
        acc[3][2] = fmaf(a3, b2, acc[3][2]); acc[3][3] = fmaf(a3, b3, acc[3][3]);
      }
      __syncthreads();
    }
  }
#pragma unroll
  for (int i = 0; i < 4; ++i) {
    int m = m0 + r0 + i;
    if (m >= BL) continue;
#pragma unroll
    for (int j = 0; j < 4; ++j)
      U[(size_t)m * D + col0 + c0 + j] += acc[i][j];
  }
}

// ---------------- LN1 -> XR ----------------
__global__ __launch_bounds__(256) void k_ln1(
    const float* __restrict__ U, const float* __restrict__ g,
    const float* __restrict__ be, float* __restrict__ XR)
{
  int row = blockIdx.x * 4 + (threadIdx.x >> 6);
  int lane = threadIdx.x & 63;
  if (row >= BL) return;
  const float* ur = U + (size_t)row * D;
  float x0 = ur[lane], x1 = ur[lane + 64];
  float mean = wsum(x0 + x1) * (1.f / D);
  float d0 = x0 - mean, d1 = x1 - mean;
  float var = wsum(d0 * d0 + d1 * d1) * (1.f / D);
  float inv = rsqrtf(var + 1e-5f);
  XR[(size_t)row * D + lane]      = d0 * inv * g[lane] + be[lane];
  XR[(size_t)row * D + lane + 64] = d1 * inv * g[lane + 64] + be[lane + 64];
}

// ---------------- FFN (relu mlp) + residual + LN2 -> U ----------------
__global__ __launch_bounds__(256) void k_ffn(
    const float* __restrict__ XR, const float* __restrict__ w1,
    const float* __restrict__ b1, const float* __restrict__ w2,
    const float* __restrict__ b2, const float* __restrict__ g2,
    const float* __restrict__ be2, float* __restrict__ U)
{
  __shared__ float xs[16][D];
  __shared__ float hs[16][DFF];
  __shared__ float os[16][D];
  int row0 = blockIdx.x * 16;
  int tid = threadIdx.x;
  for (int q = tid; q < 16 * D; q += 256) {
    int rr = q >> 7, dd = q & 127;
    int m = row0 + rr;
    xs[rr][dd] = (m < BL) ? XR[(size_t)m * D + dd] : 0.f;
  }
  __syncthreads();
  {
    float acc[16];
#pragma unroll
    for (int r = 0; r < 16; ++r) acc[r] = 0.f;
    const float* wr = w1 + (size_t)tid * D;
    for (int k = 0; k < D; ++k) {
      float wv = wr[k];
#pragma unroll
      for (int r = 0; r < 16; ++r) acc[r] = fmaf(xs[r][k], wv, acc[r]);
    }
    float bb = b1[tid];
#pragma unroll
    for (int r = 0; r < 16; ++r) hs[r][tid] = fmaxf(acc[r] + bb, 0.f);
  }
  __syncthreads();
  {
    int dd = tid & 127;
    int rg = (tid >> 7) * 8;
    float acc[8];
#pragma unroll
    for (int r = 0; r < 8; ++r) acc[r] = 0.f;
    const float* wr = w2 + (size_t)dd * DFF;
    for (int k = 0; k < DFF; ++k) {
      float wv = wr[k];
#pragma unroll
      for (int r = 0; r < 8; ++r) acc[r] = fmaf(hs[rg + r][k], wv, acc[r]);
    }
    float bb = b2[dd];
#pragma unroll
    for (int r = 0; r < 8; ++r) os[rg + r][dd] = acc[r] + bb + xs[rg + r][dd];
  }
  __syncthreads();
  {
    int r = tid >> 4, l16 = tid & 15;
    int m = row0 + r;
    float p = 0.f;
#pragma unroll
    for (int i = 0; i < 8; ++i) p += os[r][l16 * 8 + i];
#pragma unroll
    for (int mm = 1; mm < 16; mm <<= 1) p += __shfl_xor(p, mm, 64);
    float mean = p * (1.f / D);
    float qv = 0.f;
#pragma unroll
    for (int i = 0; i < 8; ++i) { float dv = os[r][l16 * 8 + i] - mean; qv += dv * dv; }
#pragma unroll
    for (int mm = 1; mm < 16; mm <<= 1) qv += __shfl_xor(qv, mm, 64);
    float inv = rsqrtf(qv * (1.f / D) + 1e-5f);
    if (m < BL) {
#pragma unroll
      for (int i = 0; i < 8; ++i) {
        int dd = l16 * 8 + i;
        U[(size_t)m * D + dd] = (os[r][dd] - mean) * inv * g2[dd] + be2[dd];
      }
    }
  }
}

// ---------------- final LN + slice + transpose -> out (B,N,D,P) ----------------
__global__ __launch_bounds__(256) void k_lnf_out(
    const float* __restrict__ U, const float* __restrict__ g,
    const float* __restrict__ be, float* __restrict__ out)
{
  int gg = blockIdx.x * 4 + (threadIdx.x >> 6);   // [0, B*2048)
  int lane = threadIdx.x & 63;
  int b = gg >> 11, t = gg & 2047;
  const float* ur = U + ((size_t)b * L + t) * D;
  float x0 = ur[lane], x1 = ur[lane + 64];
  float mean = wsum(x0 + x1) * (1.f / D);
  float d0 = x0 - mean, d1 = x1 - mean;
  float var = wsum(d0 * d0 + d1 * d1) * (1.f / D);
  float inv = rsqrtf(var + 1e-5f);
  float o0 = d0 * inv * g[lane] + be[lane];
  float o1 = d1 * inv * g[lane + 64] + be[lane + 64];
  int n = t >> 7, p = t & 127;
  size_t obase = (((size_t)b * N + n) * D) * P + p;
  out[obase + (size_t)lane * P] = o0;
  out[obase + (size_t)(lane + 64) * P] = o1;
}

extern "C" void kernel_launch(void* const* d_in, const int* in_sizes, int n_in,
                              void* d_out, int out_size, void* d_ws, size_t ws_size,
                              hipStream_t stream)
{
  (void)in_sizes; (void)n_in; (void)out_size; (void)ws_size;
  const float* x       = (const float*)d_in[0];
  const float* view    = (const float*)d_in[1];
  const float* wp_w    = (const float*)d_in[2];
  const float* wp_b    = (const float*)d_in[3];
  const float* m_in_w  = (const float*)d_in[4];
  const float* m_conv_w= (const float*)d_in[5];
  const float* m_conv_b= (const float*)d_in[6];
  const float* m_xproj = (const float*)d_in[7];
  const float* m_dt_w  = (const float*)d_in[8];
  const float* m_dt_b  = (const float*)d_in[9];
  const float* m_Alog  = (const float*)d_in[10];
  const float* m_Dp    = (const float*)d_in[11];
  const float* m_out_w = (const float*)d_in[12];
  const float* ffn_w1  = (const float*)d_in[13];
  const float* ffn_b1  = (const float*)d_in[14];
  const float* ffn_w2  = (const float*)d_in[15];
  const float* ffn_b2  = (const float*)d_in[16];
  const float* ln1_g   = (const float*)d_in[17];
  const float* ln1_b   = (const float*)d_in[18];
  const float* ln2_g   = (const float*)d_in[19];
  const float* ln2_b   = (const float*)d_in[20];
  const float* lnf_g   = (const float*)d_in[21];
  const float* lnf_b   = (const float*)d_in[22];
  float* out = (float*)d_out;

  float* W = (float*)d_ws;
  size_t off = 0;
  auto alloc = [&](size_t nfl) { float* p = W + off; off += nfl; return p; };
  float* U    = alloc((size_t)BL * D);
  float* XCP  = alloc((size_t)2 * BL * D);
  float* XCC  = alloc((size_t)2 * BL * D);
  float* Zb   = alloc((size_t)2 * BL * D);
  float* DTb  = alloc((size_t)2 * BL * D);
  float* BCb  = alloc((size_t)2 * BL * 2 * DS);
  float* DBC8 = alloc((size_t)2 * BL * DTR);
  float* XR   = alloc((size_t)BL * D);
  float* HC   = alloc((size_t)2 * B * NC * D * DS);
  float* DTS  = alloc((size_t)2 * B * NC * D);
  float* HIN  = alloc((size_t)2 * B * NC * D * DS);
  float* YM   = XCP;   // XCP is dead after k_conv; reuse for mamba y (t-space)

  k_embed<<<(BL * D + 255) / 256, 256, 0, stream>>>(x, view, wp_w, wp_b, U);

  for (int l = 0; l < EL; ++l) {
    const float* in_w_l   = m_in_w   + (size_t)l * 2 * (2 * D) * D;
    const float* conv_w_l = m_conv_w + (size_t)l * 2 * D * 2;
    const float* conv_b_l = m_conv_b + (size_t)l * 2 * D;
    const float* xproj_l  = m_xproj  + (size_t)l * 2 * (DTR + 2 * DS) * D;
    const float* dt_w_l   = m_dt_w   + (size_t)l * 2 * D * DTR;
    const float* dt_b_l   = m_dt_b   + (size_t)l * 2 * D;
    const float* Alog_l   = m_Alog   + (size_t)l * 2 * D * DS;
    const float* Dp_l     = m_Dp     + (size_t)l * 2 * D;
    const float* out_w_l  = m_out_w  + (size_t)l * 2 * D * D;

    k_xz    <<<dim3(2 * MT, (2 * D) / 64), 256, 0, stream>>>(U, in_w_l, XCP, Zb);
    k_conv  <<<(2 * BL * D) / 256, 256, 0, stream>>>(XCP, conv_w_l, conv_b_l, XCC);
    k_xproj <<<2 * MT, 256, 0, stream>>>(XCC, xproj_l, DBC8, BCb);
    k_dt    <<<(2 * BL * D) / 256, 256, 0, stream>>>(DBC8, dt_w_l, dt_b_l, DTb);
    k_scanA <<<2 * B * NC, 128, 0, stream>>>(DTb, XCC, BCb, Alog_l, HC, DTS);
    k_scanB <<<2 * B, 128, 0, stream>>>(HC, DTS, Alog_l, HIN);
    k_scanC <<<2 * B * NC, 128, 0, stream>>>(DTb, XCC, BCb, Zb, HIN, Alog_l, Dp_l, YM);
    k_outproj<<<dim3(MT, D / 64), 256, 0, stream>>>(YM, out_w_l, U);
    k_ln1   <<<(BL + 3) / 4, 256, 0, stream>>>(U, ln1_g + l * D, ln1_b + l * D, XR);
    k_ffn   <<<(BL + 15) / 16, 256, 0, stream>>>(XR, ffn_w1 + (size_t)l * DFF * D, ffn_b1 + l * DFF,
                                                 ffn_w2 + (size_t)l * D * DFF, ffn_b2 + l * D,
                                                 ln2_g + l * D, ln2_b + l * D, U);
  }
  k_lnf_out<<<(B * N * P) / 4, 256, 0, stream>>>(U, lnf_g, lnf_b, out);
}

// Round 2
// 722.284 us; speedup vs baseline: 1.2449x; 1.2449x over previous
//
#include <hip/hip_runtime.h>
#include <hip/hip_bf16.h>
#include <math.h>

#define DEV __device__ __forceinline__

constexpr int B  = 8,  N = 16, P = 128, PL = 16;
constexpr int D  = 128, DS = 16, DTR = 8, DFF = 256, EL = 2;
constexpr int L  = N * P + 1;            // 2049
constexpr int BL = B * L;                // 16392
constexpr int CT = 32;                   // scan chunk length (was 128)
constexpr int NC = (L + CT - 1) / CT;    // 65
constexpr int MT = (BL + 63) / 64;       // 257 row tiles per direction

DEV float sigmoidf_(float x) { return 1.0f / (1.0f + __expf(-x)); }

DEV float wsum(float v) {
#pragma unroll
  for (int m = 32; m; m >>= 1) v += __shfl_xor(v, m, 64);
  return v;
}

// ---------------- patch embed + view concat -> U (B,L,D) ----------------
__global__ __launch_bounds__(256) void k_embed(
    const float* __restrict__ x, const float* __restrict__ view,
    const float* __restrict__ wp_w, const float* __restrict__ wp_b,
    float* __restrict__ U)
{
  int g = blockIdx.x * 256 + threadIdx.x;
  if (g >= BL * D) return;
  int d = g & (D - 1);
  int row = g >> 7;                  // b*L + t
  int b = row / L, t = row % L;
  float acc;
  if (t < N * P) {
    const float* xr = x + ((size_t)b * N * P + t) * PL;
    acc = wp_b[d];
#pragma unroll
    for (int k = 0; k < PL; ++k) acc += xr[k] * wp_w[d * PL + k];
  } else {
    acc = view[b * D + d];
  }
  U[(size_t)row * D + d] = acc;
}

// ---------------- xz = u @ in_w.T  (gather with time reversal) ----------------
__global__ __launch_bounds__(256) void k_xz(
    const float* __restrict__ U, const float* __restrict__ in_w_l,
    float* __restrict__ XCP, float* __restrict__ Zb)
{
  __shared__ float As[64][69];
  __shared__ float Ws[64][69];
  int rdir = blockIdx.x / MT;
  int tile = blockIdx.x % MT;
  int col0 = blockIdx.y * 64;
  int tid  = threadIdx.x;
  const float* Wb = in_w_l + (size_t)rdir * (2 * D) * D;
  int m0 = tile * 64;
  int r0 = (tid >> 4) << 2, c0 = (tid & 15) << 2;
  float acc[4][4] = {};

  for (int kp = 0; kp < 2; ++kp) {
    for (int q = tid; q < 64 * 16; q += 256) {
      int rr = q >> 4, k4 = (q & 15) << 2;
      int m = m0 + rr;
      float4 v = make_float4(0.f, 0.f, 0.f, 0.f);
      if (m < BL) {
        int b = m / L, s = m % L;
        int idx = rdir ? (L - 1 - s) : s;
        v = *(const float4*)(U + ((size_t)b * L + idx) * D + kp * 64 + k4);
      }
      As[rr][k4] = v.x; As[rr][k4 + 1] = v.y; As[rr][k4 + 2] = v.z; As[rr][k4 + 3] = v.w;
      float4 w = *(const float4*)(Wb + (size_t)(col0 + rr) * D + kp * 64 + k4);
      Ws[rr][k4] = w.x; Ws[rr][k4 + 1] = w.y; Ws[rr][k4 + 2] = w.z; Ws[rr][k4 + 3] = w.w;
    }
    __syncthreads();
#pragma unroll 4
    for (int k = 0; k < 64; ++k) {
      float a0 = As[r0][k], a1 = As[r0 + 1][k], a2 = As[r0 + 2][k], a3 = As[r0 + 3][k];
      float b0 = Ws[c0][k], b1 = Ws[c0 + 1][k], b2 = Ws[c0 + 2][k], b3 = Ws[c0 + 3][k];
      acc[0][0] = fmaf(a0, b0, acc[0][0]); acc[0][1] = fmaf(a0, b1, acc[0][1]);
      acc[0][2] = fmaf(a0, b2, acc[0][2]); acc[0][3] = fmaf(a0, b3, acc[0][3]);
      acc[1][0] = fmaf(a1, b0, acc[1][0]); acc[1][1] = fmaf(a1, b1, acc[1][1]);
      acc[1][2] = fmaf(a1, b2, acc[1][2]); acc[1][3] = fmaf(a1, b3, acc[1][3]);
      acc[2][0] = fmaf(a2, b0, acc[2][0]); acc[2][1] = fmaf(a2, b1, acc[2][1]);
      acc[2][2] = fmaf(a2, b2, acc[2][2]); acc[2][3] = fmaf(a2, b3, acc[2][3]);
      acc[3][0] = fmaf(a3, b0, acc[3][0]); acc[3][1] = fmaf(a3, b1, acc[3][1]);
      acc[3][2] = fmaf(a3, b2, acc[3][2]); acc[3][3] = fmaf(a3, b3, acc[3][3]);
    }
    __syncthreads();
  }
#pragma unroll
  for (int i = 0; i < 4; ++i) {
    int m = m0 + r0 + i;
    if (m >= BL) continue;
    size_t base = ((size_t)rdir * BL + m) * D;
#pragma unroll
    for (int j = 0; j < 4; ++j) {
      int col = col0 + c0 + j;
      if (col < D) XCP[base + col] = acc[i][j];
      else         Zb[base + col - D] = acc[i][j];
    }
  }
}

// ---------------- depthwise conv(2) + silu ----------------
__global__ __launch_bounds__(256) void k_conv(
    const float* __restrict__ XCP, const float* __restrict__ conv_w_l,
    const float* __restrict__ conv_b_l, float* __restrict__ XCC)
{
  int g = blockIdx.x * 256 + threadIdx.x;      // 2*BL*D
  if (g >= 2 * BL * D) return;
  int d = g & 127;
  int row = g >> 7;
  int rdir = row / BL;
  int s = row % L;
  const float* cw = conv_w_l + rdir * D * 2;
  float cur  = XCP[(size_t)row * D + d];
  float prev = (s > 0) ? XCP[((size_t)row - 1) * D + d] : 0.f;
  float v = prev * cw[2 * d] + cur * cw[2 * d + 1] + conv_b_l[rdir * D + d];
  XCC[(size_t)g] = v * sigmoidf_(v);
}

// ---------------- dbc = xcc @ xproj_w.T -> DBC8 (cols<8), BC (cols 8..39) ----------------
__global__ __launch_bounds__(256) void k_xproj(
    const float* __restrict__ XCC, const float* __restrict__ xproj_w_l,
    float* __restrict__ DBC8, float* __restrict__ BCb)
{
  __shared__ float As[64][69];
  __shared__ float Ws[64][69];
  int rdir = blockIdx.x / MT;
  int tile = blockIdx.x % MT;
  int tid  = threadIdx.x;
  const float* Wb = xproj_w_l + (size_t)rdir * (DTR + 2 * DS) * D;
  int m0 = tile * 64;
  int r0 = (tid >> 4) << 2, c0 = (tid & 15) << 2;
  float acc[4][4] = {};

  for (int kp = 0; kp < 2; ++kp) {
    for (int q = tid; q < 64 * 16; q += 256) {
      int rr = q >> 4, k4 = (q & 15) << 2;
      int m = m0 + rr;
      float4 v = make_float4(0.f, 0.f, 0.f, 0.f);
      if (m < BL) v = *(const float4*)(XCC + ((size_t)rdir * BL + m) * D + kp * 64 + k4);
      As[rr][k4] = v.x; As[rr][k4 + 1] = v.y; As[rr][k4 + 2] = v.z; As[rr][k4 + 3] = v.w;
      float4 w = make_float4(0.f, 0.f, 0.f, 0.f);
      if (rr < DTR + 2 * DS) w = *(const float4*)(Wb + (size_t)rr * D + kp * 64 + k4);
      Ws[rr][k4] = w.x; Ws[rr][k4 + 1] = w.y; Ws[rr][k4 + 2] = w.z; Ws[rr][k4 + 3] = w.w;
    }
    __syncthreads();
#pragma unroll 4
    for (int k = 0; k < 64; ++k) {
      float a0 = As[r0][k], a1 = As[r0 + 1][k], a2 = As[r0 + 2][k], a3 = As[r0 + 3][k];
      float b0 = Ws[c0][k], b1 = Ws[c0 + 1][k], b2 = Ws[c0 + 2][k], b3 = Ws[c0 + 3][k];
      acc[0][0] = fmaf(a0, b0, acc[0][0]); acc[0][1] = fmaf(a0, b1, acc[0][1]);
      acc[0][2] = fmaf(a0, b2, acc[0][2]); acc[0][3] = fmaf(a0, b3, acc[0][3]);
      acc[1][0] = fmaf(a1, b0, acc[1][0]); acc[1][1] = fmaf(a1, b1, acc[1][1]);
      acc[1][2] = fmaf(a1, b2, acc[1][2]); acc[1][3] = fmaf(a1, b3, acc[1][3]);
      acc[2][0] = fmaf(a2, b0, acc[2][0]); acc[2][1] = fmaf(a2, b1, acc[2][1]);
      acc[2][2] = fmaf(a2, b2, acc[2][2]); acc[2][3] = fmaf(a2, b3, acc[2][3]);
      acc[3][0] = fmaf(a3, b0, acc[3][0]); acc[3][1] = fmaf(a3, b1, acc[3][1]);
      acc[3][2] = fmaf(a3, b2, acc[3][2]); acc[3][3] = fmaf(a3, b3, acc[3][3]);
    }
    __syncthreads();
  }
#pragma unroll
  for (int i = 0; i < 4; ++i) {
    int m = m0 + r0 + i;
    if (m >= BL) continue;
    size_t rowi = (size_t)rdir * BL + m;
#pragma unroll
    for (int j = 0; j < 4; ++j) {
      int col = c0 + j;
      if (col < DTR) DBC8[rowi * 8 + col] = acc[i][j];
      else if (col < DTR + 2 * DS) BCb[rowi * 32 + (col - DTR)] = acc[i][j];
    }
  }
}

// ---------------- dt = softplus(dbc8 @ dt_w.T + dt_b) ----------------
__global__ __launch_bounds__(256) void k_dt(
    const float* __restrict__ DBC8, const float* __restrict__ dt_w_l,
    const float* __restrict__ dt_b_l, float* __restrict__ DT)
{
  int g = blockIdx.x * 256 + threadIdx.x;    // 2*BL*D
  if (g >= 2 * BL * D) return;
  int d = g & 127;
  int row = g >> 7;
  int rdir = row / BL;
  const float* db = DBC8 + (size_t)row * 8;
  const float* dw = dt_w_l + (size_t)rdir * D * DTR + d * DTR;
  float a = dt_b_l[rdir * D + d];
#pragma unroll
  for (int j = 0; j < DTR; ++j) a += db[j] * dw[j];
  DT[(size_t)g] = (a > 20.f) ? a : log1pf(__expf(a));
}

// A_n check: inputs are A_init = log(1..16) broadcast, so A_n = -(n+1) exactly.
// Verified at runtime (wave-uniform); falls back to generic exp path otherwise.
DEV bool an_is_linear(const float* An) {
  bool ok = true;
#pragma unroll
  for (int n = 0; n < DS; ++n)
    ok = ok && (fabsf(An[n] + (float)(n + 1)) < 1e-3f * (n + 1));
  return ok;
}

// ---------------- scan phase A: per-chunk local end state + sum(dt) ----------------
__global__ __launch_bounds__(128) void k_scanA(
    const float* __restrict__ DT, const float* __restrict__ XCC,
    const float* __restrict__ BCb, const float* __restrict__ Alog_l,
    float* __restrict__ HC, float* __restrict__ DTS)
{
  __shared__ float Bs[CT][DS];
  int blk = blockIdx.x;                 // (rdir*B+b)*NC + c
  int c  = blk % NC;
  int rb = blk / NC;
  int rdir = rb / B;
  int d = threadIdx.x;
  int s0 = c * CT;
  int cnt = min(CT, L - s0);
  size_t rowbase = (size_t)rb * L + s0;
  for (int q = d; q < cnt * DS; q += 128)
    Bs[q >> 4][q & 15] = BCb[(rowbase + (q >> 4)) * 32 + (q & 15)];
  float An[DS];
  const float* Ab = Alog_l + (size_t)rdir * D * DS + (size_t)d * DS;
#pragma unroll
  for (int n = 0; n < DS; ++n) An[n] = -__expf(Ab[n]);
  bool fast = an_is_linear(An);
  __syncthreads();
  float h[DS];
#pragma unroll
  for (int n = 0; n < DS; ++n) h[n] = 0.f;
  float dts = 0.f;
  // 1-deep prefetch of dt/xc
  float dt_nx = DT[rowbase * D + d];
  float xc_nx = XCC[rowbase * D + d];
  if (fast) {
    for (int ss = 0; ss < cnt; ++ss) {
      float dt = dt_nx, xc = xc_nx;
      if (ss + 1 < cnt) {
        size_t ro = (rowbase + ss + 1) * D + d;
        dt_nx = DT[ro]; xc_nx = XCC[ro];
      }
      dts += dt;
      float e = dt * xc;
      float r = __expf(-dt);
      float p = r;
#pragma unroll
      for (int n = 0; n < DS; ++n) {
        h[n] = p * h[n] + e * Bs[ss][n];
        p *= r;
      }
    }
  } else {
    for (int ss = 0; ss < cnt; ++ss) {
      float dt = dt_nx, xc = xc_nx;
      if (ss + 1 < cnt) {
        size_t ro = (rowbase + ss + 1) * D + d;
        dt_nx = DT[ro]; xc_nx = XCC[ro];
      }
      dts += dt;
      float e = dt * xc;
#pragma unroll
      for (int n = 0; n < DS; ++n)
        h[n] = __expf(dt * An[n]) * h[n] + e * Bs[ss][n];
    }
  }
  float* hp = HC + ((size_t)blk * D + d) * DS;
#pragma unroll
  for (int n = 0; n < DS; ++n) hp[n] = h[n];
  DTS[(size_t)blk * D + d] = dts;
}

// ---------------- scan phase B: propagate chunk boundary states ----------------
__global__ __launch_bounds__(128) void k_scanB(
    const float* __restrict__ HC, const float* __restrict__ DTS,
    const float* __restrict__ Alog_l, float* __restrict__ HIN)
{
  int rb = blockIdx.x;                  // 2*B
  int rdir = rb / B;
  int d = threadIdx.x;
  float An[DS];
  const float* Ab = Alog_l + (size_t)rdir * D * DS + (size_t)d * DS;
#pragma unroll
  for (int n = 0; n < DS; ++n) An[n] = -__expf(Ab[n]);
  bool fast = an_is_linear(An);
  float h[DS];
#pragma unroll
  for (int n = 0; n < DS; ++n) h[n] = 0.f;
  // prefetch chunk 0
  size_t i0 = ((size_t)(rb * NC) * D + d) * DS;
  float dts_nx = DTS[(size_t)(rb * NC) * D + d];
  float4 h0 = *(const float4*)(HC + i0);
  float4 h1 = *(const float4*)(HC + i0 + 4);
  float4 h2 = *(const float4*)(HC + i0 + 8);
  float4 h3 = *(const float4*)(HC + i0 + 12);
  for (int c = 0; c < NC; ++c) {
    size_t idx = ((size_t)(rb * NC + c) * D + d) * DS;
    float* hin = HIN + idx;
    float hc[DS];
    hc[0]=h0.x; hc[1]=h0.y; hc[2]=h0.z; hc[3]=h0.w;
    hc[4]=h1.x; hc[5]=h1.y; hc[6]=h1.z; hc[7]=h1.w;
    hc[8]=h2.x; hc[9]=h2.y; hc[10]=h2.z; hc[11]=h2.w;
    hc[12]=h3.x; hc[13]=h3.y; hc[14]=h3.z; hc[15]=h3.w;
    float dts = dts_nx;
    if (c + 1 < NC) {
      size_t in = ((size_t)(rb * NC + c + 1) * D + d) * DS;
      dts_nx = DTS[(size_t)(rb * NC + c + 1) * D + d];
      h0 = *(const float4*)(HC + in);
      h1 = *(const float4*)(HC + in + 4);
      h2 = *(const float4*)(HC + in + 8);
      h3 = *(const float4*)(HC + in + 12);
    }
#pragma unroll
    for (int n = 0; n < DS; ++n) hin[n] = h[n];
    if (fast) {
      float r = __expf(-dts);
      float p = r;
#pragma unroll
      for (int n = 0; n < DS; ++n) {
        h[n] = p * h[n] + hc[n];
        p *= r;
      }
    } else {
#pragma unroll
      for (int n = 0; n < DS; ++n)
        h[n] = __expf(dts * An[n]) * h[n] + hc[n];
    }
  }
}

// ---------------- scan phase C: full scan seeded with h_in, emit y (t-space) ----------------
__global__ __launch_bounds__(128) void k_scanC(
    const float* __restrict__ DT, const float* __restrict__ XCC,
    const float* __restrict__ BCb, const float* __restrict__ Zb,
    const float* __restrict__ HIN, const float* __restrict__ Alog_l,
    const float* __restrict__ Dp_l, float* __restrict__ YM)
{
  __shared__ float Bs[CT][DS];
  __shared__ float Cs[CT][DS];
  int blk = blockIdx.x;
  int c  = blk % NC;
  int rb = blk / NC;
  int rdir = rb / B;
  int b = rb % B;
  int d = threadIdx.x;
  int s0 = c * CT;
  int cnt = min(CT, L - s0);
  size_t rowbase = (size_t)rb * L + s0;
  for (int q = d; q < cnt * 2 * DS; q += 128) {
    int ss = q >> 5, j = q & 31;
    float vv = BCb[(rowbase + ss) * 32 + j];
    if (j < DS) Bs[ss][j] = vv; else Cs[ss][j - DS] = vv;
  }
  float An[DS];
  const float* Ab = Alog_l + (size_t)rdir * D * DS + (size_t)d * DS;
#pragma unroll
  for (int n = 0; n < DS; ++n) An[n] = -__expf(Ab[n]);
  bool fast = an_is_linear(An);
  float h[DS];
  const float* hin = HIN + ((size_t)blk * D + d) * DS;
#pragma unroll
  for (int n = 0; n < DS; ++n) h[n] = hin[n];
  float Dpv = Dp_l[rdir * D + d];
  __syncthreads();
  float dt_nx = DT[rowbase * D + d];
  float xc_nx = XCC[rowbase * D + d];
  float z_nx  = Zb[rowbase * D + d];
  if (fast) {
    for (int ss = 0; ss < cnt; ++ss) {
      float dt = dt_nx, xc = xc_nx, z = z_nx;
      if (ss + 1 < cnt) {
        size_t ro = (rowbase + ss + 1) * D + d;
        dt_nx = DT[ro]; xc_nx = XCC[ro]; z_nx = Zb[ro];
      }
      float e = dt * xc;
      float r = __expf(-dt);
      float p = r;
      float y = 0.f;
#pragma unroll
      for (int n = 0; n < DS; ++n) {
        h[n] = p * h[n] + e * Bs[ss][n];
        y += h[n] * Cs[ss][n];
        p *= r;
      }
      y += xc * Dpv;
      y *= z * sigmoidf_(z);
      int s = s0 + ss;
      int tt = rdir ? (L - 1 - s) : s;
      YM[((size_t)rdir * BL + (size_t)b * L + tt) * D + d] = y;
    }
  } else {
    for (int ss = 0; ss < cnt; ++ss) {
      float dt = dt_nx, xc = xc_nx, z = z_nx;
      if (ss + 1 < cnt) {
        size_t ro = (rowbase + ss + 1) * D + d;
        dt_nx = DT[ro]; xc_nx = XCC[ro]; z_nx = Zb[ro];
      }
      float e = dt * xc;
      float y = 0.f;
#pragma unroll
      for (int n = 0; n < DS; ++n) {
        h[n] = __expf(dt * An[n]) * h[n] + e * Bs[ss][n];
        y += h[n] * Cs[ss][n];
      }
      y += xc * Dpv;
      y *= z * sigmoidf_(z);
      int s = s0 + ss;
      int tt = rdir ? (L - 1 - s) : s;
      YM[((size_t)rdir * BL + (size_t)b * L + tt) * D + d] = y;
    }
  }
}

// ---------------- out-proj both dirs, accumulate into U ----------------
__global__ __launch_bounds__(256) void k_outproj(
    const float* __restrict__ YM, const float* __restrict__ out_w_l,
    float* __restrict__ U)
{
  __shared__ float As[64][69];
  __shared__ float Ws[64][69];
  int tile = blockIdx.x;
  int col0 = blockIdx.y * 64;
  int tid  = threadIdx.x;
  int m0 = tile * 64;
  int r0 = (tid >> 4) << 2, c0 = (tid & 15) << 2;
  float acc[4][4] = {};
  for (int dir = 0; dir < 2; ++dir) {
    const float* Wb = out_w_l + (size_t)dir * D * D;
    const float* Abase = YM + (size_t)dir * BL * D;
    for (int kp = 0; kp < 2; ++kp) {
      for (int q = tid; q < 64 * 16; q += 256) {
        int rr = q >> 4, k4 = (q & 15) << 2;
        int m = m0 + rr;
        float4 v = make_float4(0.f, 0.f, 0.f, 0.f);
        if (m < BL) v = *(const float4*)(Abase + (size_t)m * D + kp * 64 + k4);
        As[rr][k4] = v.x; As[rr][k4 + 1] = v.y; As[rr][k4 + 2] = v.z; As[rr][k4 + 3] = v.w;
        float4 w = *(const float4*)(Wb + (size_t)(col0 + rr) * D + kp * 64 + k4);
        Ws[rr][k4] = w.x; Ws[rr][k4 + 1] = w.y; Ws[rr][k4 + 2] = w.z; Ws[rr][k4 + 3] = w.w;
      }
      __syncthreads();
#pragma unroll 4
      for (int k = 0; k < 64; ++k) {
        float a0 = As[r0][k], a1 = As[r0 + 1][k], a2 = As[r0 + 2][k], a3 = As[r0 + 3][k];
        float b0 = Ws[c0][k], b1 = Ws[c0 + 1][k], b2 = Ws[c0 + 2][k], b3 = Ws[c0 + 3][k];
        acc[0][0] = fmaf(a0, b0, acc[0][0]); acc[0][1] = fmaf(a0, b1, acc[0][1]);
        acc[0][2] = fmaf(a0, b2, acc[0][2]); acc[0][3] = fmaf(a0, b3, acc[0][3]);
        acc[1][0] = fmaf(a1, b0, acc[1][0]); acc[1][1] = fmaf(a1, b1, acc[1][1]);
        acc[1][2] = fmaf(a1, b2, acc[1][2]); acc[1][3] = fmaf(a1, b3, acc[1][3]);
        acc[2][0] = fmaf(a2, b0, acc[2][0]); acc[2][1] = fmaf(a2, b1, acc[2][1]);
        acc[2][2] = fmaf(a2, b2, acc[2][2]); acc[2][3] = fmaf(a2, b3, acc[2][3]);
        acc[3][0] = fmaf(a3, b0, acc[3][0]); acc[3][1] = fmaf(a3, b1, acc[3][1]);
        acc[3][2] = fmaf(a3, b2, acc[3][2]); acc[3][3] = fmaf(a3, b3, acc[3][3]);
      }
      __syncthreads();
    }
  }
#pragma unroll
  for (int i = 0; i < 4; ++i) {
    int m = m0 + r0 + i;
    if (m >= BL) continue;
#pragma unroll
    for (int j = 0; j < 4; ++j)
      U[(size_t)m * D + col0 + c0 + j] += acc[i][j];
  }
}

// ---------------- LN1 -> XR ----------------
__global__ __launch_bounds__(256) void k_ln1(
    const float* __restrict__ U, const float* __restrict__ g,
    const float* __restrict__ be, float* __restrict__ XR)
{
  int row = blockIdx.x * 4 + (threadIdx.x >> 6);
  int lane = threadIdx.x & 63;
  if (row >= BL) return;
  const float* ur = U + (size_t)row * D;
  float x0 = ur[lane], x1 = ur[lane + 64];
  float mean = wsum(x0 + x1) * (1.f / D);
  float d0 = x0 - mean, d1 = x1 - mean;
  float var = wsum(d0 * d0 + d1 * d1) * (1.f / D);
  float inv = rsqrtf(var + 1e-5f);
  XR[(size_t)row * D + lane]      = d0 * inv * g[lane] + be[lane];
  XR[(size_t)row * D + lane + 64] = d1 * inv * g[lane + 64] + be[lane + 64];
}

// ---------------- FFN (relu mlp) + residual + LN2 -> U ----------------
__global__ __launch_bounds__(256) void k_ffn(
    const float* __restrict__ XR, const float* __restrict__ w1,
    const float* __restrict__ b1, const float* __restrict__ w2,
    const float* __restrict__ b2, const float* __restrict__ g2,
    const float* __restrict__ be2, float* __restrict__ U)
{
  __shared__ __align__(16) float xs[16][D];
  __shared__ __align__(16) float hs[16][DFF];
  __shared__ __align__(16) float os[16][D];
  int row0 = blockIdx.x * 16;
  int tid = threadIdx.x;
  for (int q = tid; q < 16 * D; q += 256) {
    int rr = q >> 7, dd = q & 127;
    int m = row0 + rr;
    xs[rr][dd] = (m < BL) ? XR[(size_t)m * D + dd] : 0.f;
  }
  __syncthreads();
  {
    float acc[16];
#pragma unroll
    for (int r = 0; r < 16; ++r) acc[r] = 0.f;
    const float4* wr4 = (const float4*)(w1 + (size_t)tid * D);
    for (int kk = 0; kk < D / 4; ++kk) {
      float4 wv = wr4[kk];
#pragma unroll
      for (int r = 0; r < 16; ++r) {
        float4 xv = *(const float4*)&xs[r][kk * 4];
        acc[r] = fmaf(xv.x, wv.x, acc[r]);
        acc[r] = fmaf(xv.y, wv.y, acc[r]);
        acc[r] = fmaf(xv.z, wv.z, acc[r]);
        acc[r] = fmaf(xv.w, wv.w, acc[r]);
      }
    }
    float bb = b1[tid];
#pragma unroll
    for (int r = 0; r < 16; ++r) hs[r][tid] = fmaxf(acc[r] + bb, 0.f);
  }
  __syncthreads();
  {
    int dd = tid & 127;
    int rg = (tid >> 7) * 8;
    float acc[8];
#pragma unroll
    for (int r = 0; r < 8; ++r) acc[r] = 0.f;
    const float4* wr4 = (const float4*)(w2 + (size_t)dd * DFF);
    for (int kk = 0; kk < DFF / 4; ++kk) {
      float4 wv = wr4[kk];
#pragma unroll
      for (int r = 0; r < 8; ++r) {
        float4 hv = *(const float4*)&hs[rg + r][kk * 4];
        acc[r] = fmaf(hv.x, wv.x, acc[r]);
        acc[r] = fmaf(hv.y, wv.y, acc[r]);
        acc[r] = fmaf(hv.z, wv.z, acc[r]);
        acc[r] = fmaf(hv.w, wv.w, acc[r]);
      }
    }
    float bb = b2[dd];
#pragma unroll
    for (int r = 0; r < 8; ++r) os[rg + r][dd] = acc[r] + bb + xs[rg + r][dd];
  }
  __syncthreads();
  {
    int r = tid >> 4, l16 = tid & 15;
    int m = row0 + r;
    float p = 0.f;
#pragma unroll
    for (int i = 0; i < 8; ++i) p += os[r][l16 * 8 + i];
#pragma unroll
    for (int mm = 1; mm < 16; mm <<= 1) p += __shfl_xor(p, mm, 64);
    float mean = p * (1.f / D);
    float qv = 0.f;
#pragma unroll
    for (int i = 0; i < 8; ++i) { float dv = os[r][l16 * 8 + i] - mean; qv += dv * dv; }
#pragma unroll
    for (int mm = 1; mm < 16; mm <<= 1) qv += __shfl_xor(qv, mm, 64);
    float inv = rsqrtf(qv * (1.f / D) + 1e-5f);
    if (m < BL) {
#pragma unroll
      for (int i = 0; i < 8; ++i) {
        int dd = l16 * 8 + i;
        U[(size_t)m * D + dd] = (os[r][dd] - mean) * inv * g2[dd] + be2[dd];
      }
    }
  }
}

// ---------------- final LN + slice + transpose -> out (B,N,D,P) ----------------
__global__ __launch_bounds__(256) void k_lnf_out(
    const float* __restrict__ U, const float* __restrict__ g,
    const float* __restrict__ be, float* __restrict__ out)
{
  int gg = blockIdx.x * 4 + (threadIdx.x >> 6);   // [0, B*2048)
  int lane = threadIdx.x & 63;
  int b = gg >> 11, t = gg & 2047;
  const float* ur = U + ((size_t)b * L + t) * D;
  float x0 = ur[lane], x1 = ur[lane + 64];
  float mean = wsum(x0 + x1) * (1.f / D);
  float d0 = x0 - mean, d1 = x1 - mean;
  float var = wsum(d0 * d0 + d1 * d1) * (1.f / D);
  float inv = rsqrtf(var + 1e-5f);
  float o0 = d0 * inv * g[lane] + be[lane];
  float o1 = d1 * inv * g[lane + 64] + be[lane + 64];
  int n = t >> 7, p = t & 127;
  size_t obase = (((size_t)b * N + n) * D) * P + p;
  out[obase + (size_t)lane * P] = o0;
  out[obase + (size_t)(lane + 64) * P] = o1;
}

extern "C" void kernel_launch(void* const* d_in, const int* in_sizes, int n_in,
                              void* d_out, int out_size, void* d_ws, size_t ws_size,
                              hipStream_t stream)
{
  (void)in_sizes; (void)n_in; (void)out_size; (void)ws_size;
  const float* x       = (const float*)d_in[0];
  const float* view    = (const float*)d_in[1];
  const float* wp_w    = (const float*)d_in[2];
  const float* wp_b    = (const float*)d_in[3];
  const float* m_in_w  = (const float*)d_in[4];
  const float* m_conv_w= (const float*)d_in[5];
  const float* m_conv_b= (const float*)d_in[6];
  const float* m_xproj = (const float*)d_in[7];
  const float* m_dt_w  = (const float*)d_in[8];
  const float* m_dt_b  = (const float*)d_in[9];
  const float* m_Alog  = (const float*)d_in[10];
  const float* m_Dp    = (const float*)d_in[11];
  const float* m_out_w = (const float*)d_in[12];
  const float* ffn_w1  = (const float*)d_in[13];
  const float* ffn_b1  = (const float*)d_in[14];
  const float* ffn_w2  = (const float*)d_in[15];
  const float* ffn_b2  = (const float*)d_in[16];
  const float* ln1_g   = (const float*)d_in[17];
  const float* ln1_b   = (const float*)d_in[18];
  const float* ln2_g   = (const float*)d_in[19];
  const float* ln2_b   = (const float*)d_in[20];
  const float* lnf_g   = (const float*)d_in[21];
  const float* lnf_b   = (const float*)d_in[22];
  float* out = (float*)d_out;

  float* W = (float*)d_ws;
  size_t off = 0;
  auto alloc = [&](size_t nfl) { float* p = W + off; off += nfl; return p; };
  float* U    = alloc((size_t)BL * D);
  float* XCP  = alloc((size_t)2 * BL * D);
  float* XCC  = alloc((size_t)2 * BL * D);
  float* Zb   = alloc((size_t)2 * BL * D);
  float* DTb  = alloc((size_t)2 * BL * D);
  float* BCb  = alloc((size_t)2 * BL * 2 * DS);
  float* DBC8 = alloc((size_t)2 * BL * DTR);
  float* XR   = alloc((size_t)BL * D);
  float* HC   = alloc((size_t)2 * B * NC * D * DS);
  float* DTS  = alloc((size_t)2 * B * NC * D);
  float* HIN  = alloc((size_t)2 * B * NC * D * DS);
  float* YM   = XCP;   // XCP is dead after k_conv; reuse for mamba y (t-space)

  k_embed<<<(BL * D + 255) / 256, 256, 0, stream>>>(x, view, wp_w, wp_b, U);

  for (int l = 0; l < EL; ++l) {
    const float* in_w_l   = m_in_w   + (size_t)l * 2 * (2 * D) * D;
    const float* conv_w_l = m_conv_w + (size_t)l * 2 * D * 2;
    const float* conv_b_l = m_conv_b + (size_t)l * 2 * D;
    const float* xproj_l  = m_xproj  + (size_t)l * 2 * (DTR + 2 * DS) * D;
    const float* dt_w_l   = m_dt_w   + (size_t)l * 2 * D * DTR;
    const float* dt_b_l   = m_dt_b   + (size_t)l * 2 * D;
    const float* Alog_l   = m_Alog   + (size_t)l * 2 * D * DS;
    const float* Dp_l     = m_Dp     + (size_t)l * 2 * D;
    const float* out_w_l  = m_out_w  + (size_t)l * 2 * D * D;

    k_xz    <<<dim3(2 * MT, (2 * D) / 64), 256, 0, stream>>>(U, in_w_l, XCP, Zb);
    k_conv  <<<(2 * BL * D) / 256, 256, 0, stream>>>(XCP, conv_w_l, conv_b_l, XCC);
    k_xproj <<<2 * MT, 256, 0, stream>>>(XCC, xproj_l, DBC8, BCb);
    k_dt    <<<(2 * BL * D) / 256, 256, 0, stream>>>(DBC8, dt_w_l, dt_b_l, DTb);
    k_scanA <<<2 * B * NC, 128, 0, stream>>>(DTb, XCC, BCb, Alog_l, HC, DTS);
    k_scanB <<<2 * B, 128, 0, stream>>>(HC, DTS, Alog_l, HIN);
    k_scanC <<<2 * B * NC, 128, 0, stream>>>(DTb, XCC, BCb, Zb, HIN, Alog_l, Dp_l, YM);
    k_outproj<<<dim3(MT, D / 64), 256, 0, stream>>>(YM, out_w_l, U);
    k_ln1   <<<(BL + 3) / 4, 256, 0, stream>>>(U, ln1_g + l * D, ln1_b + l * D, XR);
    k_ffn   <<<(BL + 15) / 16, 256, 0, stream>>>(XR, ffn_w1 + (size_t)l * DFF * D, ffn_b1 + l * DFF,
                                                 ffn_w2 + (size_t)l * D * DFF, ffn_b2 + l * D,
                                                 ln2_g + l * D, ln2_b + l * D, U);
  }
  k_lnf_out<<<(B * N * P) / 4, 256, 0, stream>>>(U, lnf_g, lnf_b, out);
}

// Round 3
// 462.335 us; speedup vs baseline: 1.9449x; 1.5623x over previous
//
#include <hip/hip_runtime.h>
#include <hip/hip_bf16.h>
#include <math.h>

#define DEV __device__ __forceinline__

constexpr int B  = 8,  N = 16, P = 128, PL = 16;
constexpr int D  = 128, DS = 16, DTR = 8, DFF = 256, EL = 2;
constexpr int L  = N * P + 1;            // 2049
constexpr int BL = B * L;                // 16392
constexpr int CT = 32;                   // scan chunk length
constexpr int NC = (L + CT - 1) / CT;    // 65
constexpr int MT128 = (BL + 127) / 128;  // 129
constexpr int MT64  = (BL + 63) / 64;    // 257
constexpr int KS = 136;                  // LDS row stride (bf16) for 128-wide K chunk

using bf16x8 = __attribute__((ext_vector_type(8))) __bf16;
using f32x4  = __attribute__((ext_vector_type(4))) float;

DEV float sigmoidf_(float x) { return 1.0f / (1.0f + __expf(-x)); }

DEV float wsum(float v) {
#pragma unroll
  for (int m = 32; m; m >>= 1) v += __shfl_xor(v, m, 64);
  return v;
}

// ---------------- weight prep: fp32 -> bf16 (+ outw layout transform) ----------------
__global__ __launch_bounds__(256) void k_prep(
    const float* __restrict__ in_w, const float* __restrict__ xproj,
    const float* __restrict__ out_w, const float* __restrict__ w1,
    const float* __restrict__ w2,
    __bf16* __restrict__ inw_bf, __bf16* __restrict__ xpw_bf,
    __bf16* __restrict__ outw_bf, __bf16* __restrict__ w1_bf,
    __bf16* __restrict__ w2_bf)
{
  int g = blockIdx.x * 256 + threadIdx.x;
  if (g < 131072) { inw_bf[g] = (__bf16)in_w[g]; return; }
  g -= 131072;
  if (g < 20480) { xpw_bf[g] = (__bf16)xproj[g]; return; }
  g -= 20480;
  if (g < 65536) {
    // src flat over (l,dir,n,k); dst [l][n][dir*128+k]
    int k = g & 127; int q = g >> 7; int n = q & 127; int q2 = q >> 7;
    int dir = q2 & 1; int l = q2 >> 1;
    outw_bf[((size_t)(l * 128 + n)) * 256 + dir * 128 + k] = (__bf16)out_w[g];
    return;
  }
  g -= 65536;
  if (g < 65536) { w1_bf[g] = (__bf16)w1[g]; return; }
  g -= 65536;
  if (g < 65536) { w2_bf[g] = (__bf16)w2[g]; return; }
}

// ---------------- patch embed + view concat -> U (fp32) + Ubf (bf16) ----------------
__global__ __launch_bounds__(256) void k_embed(
    const float* __restrict__ x, const float* __restrict__ view,
    const float* __restrict__ wp_w, const float* __restrict__ wp_b,
    float* __restrict__ U, __bf16* __restrict__ Ubf)
{
  int g = blockIdx.x * 256 + threadIdx.x;
  if (g >= BL * D) return;
  int d = g & (D - 1);
  int row = g >> 7;
  int b = row / L, t = row % L;
  float acc;
  if (t < N * P) {
    const float* xr = x + ((size_t)b * N * P + t) * PL;
    acc = wp_b[d];
#pragma unroll
    for (int k = 0; k < PL; ++k) acc += xr[k] * wp_w[d * PL + k];
  } else {
    acc = view[b * D + d];
  }
  U[(size_t)row * D + d] = acc;
  Ubf[(size_t)row * D + d] = (__bf16)acc;
}

// ---------------- xz = u @ in_w.T (MFMA, gather w/ reversal) ----------------
// grid (2*MT128, 4): writes XCP (col<128) and Zb (col>=128), rows in s-space
__global__ __launch_bounds__(256) void k_xz_mfma(
    const __bf16* __restrict__ Ubf, const __bf16* __restrict__ Wbf,
    float* __restrict__ XCP, float* __restrict__ Zb)
{
  __shared__ short As[128 * KS];
  __shared__ short Bs[64 * KS];
  int bx = blockIdx.x;
  int rdir = bx / MT128;
  int tile = bx % MT128;
  int col0 = blockIdx.y * 64;
  int tid = threadIdx.x;
  int m0 = tile * 128;
  const __bf16* Wb = Wbf + (size_t)rdir * 256 * 128;
  for (int q = tid; q < 128 * 16; q += 256) {
    int rr = q >> 4, g = q & 15;
    int m = m0 + rr;
    int4 v = make_int4(0, 0, 0, 0);
    if (m < BL) {
      int b = m / L, s = m - b * L;
      int idx = rdir ? (L - 1 - s) : s;
      v = *(const int4*)(Ubf + ((size_t)b * L + idx) * 128 + g * 8);
    }
    *(int4*)&As[rr * KS + g * 8] = v;
  }
  for (int q = tid; q < 64 * 16; q += 256) {
    int rr = q >> 4, g = q & 15;
    int4 v = *(const int4*)(Wb + (size_t)(col0 + rr) * 128 + g * 8);
    *(int4*)&Bs[rr * KS + g * 8] = v;
  }
  __syncthreads();
  int wave = tid >> 6, lane = tid & 63, lm = lane & 15, lq = lane >> 4;
  f32x4 zero4 = {0.f, 0.f, 0.f, 0.f};
  f32x4 acc[2][4];
#pragma unroll
  for (int r = 0; r < 2; ++r)
#pragma unroll
    for (int c = 0; c < 4; ++c) acc[r][c] = zero4;
  for (int ks = 0; ks < 128; ks += 32) {
    bf16x8 af[2];
#pragma unroll
    for (int r = 0; r < 2; ++r)
      af[r] = *(const bf16x8*)&As[(wave * 32 + r * 16 + lm) * KS + ks + lq * 8];
#pragma unroll
    for (int c = 0; c < 4; ++c) {
      bf16x8 bfr = *(const bf16x8*)&Bs[(c * 16 + lm) * KS + ks + lq * 8];
#pragma unroll
      for (int r = 0; r < 2; ++r)
        acc[r][c] = __builtin_amdgcn_mfma_f32_16x16x32_bf16(af[r], bfr, acc[r][c], 0, 0, 0);
    }
  }
#pragma unroll
  for (int r = 0; r < 2; ++r) {
    int rowb = m0 + wave * 32 + r * 16 + lq * 4;
#pragma unroll
    for (int c = 0; c < 4; ++c) {
      int col = col0 + c * 16 + lm;
#pragma unroll
      for (int e = 0; e < 4; ++e) {
        int m = rowb + e;
        if (m < BL) {
          size_t base = ((size_t)rdir * BL + m) * 128;
          float v = acc[r][c][e];
          if (col < 128) XCP[base + col] = v;
          else           Zb[base + col - 128] = v;
        }
      }
    }
  }
}

// ---------------- depthwise conv(2) + silu -> XCC fp32 + bf16 ----------------
__global__ __launch_bounds__(256) void k_conv(
    const float* __restrict__ XCP, const float* __restrict__ conv_w_l,
    const float* __restrict__ conv_b_l, float* __restrict__ XCC,
    __bf16* __restrict__ XCCbf)
{
  int g = blockIdx.x * 256 + threadIdx.x;      // 2*BL*D
  if (g >= 2 * BL * D) return;
  int d = g & 127;
  int row = g >> 7;
  int rdir = row / BL;
  int s = row % L;
  const float* cw = conv_w_l + rdir * D * 2;
  float cur  = XCP[(size_t)row * D + d];
  float prev = (s > 0) ? XCP[((size_t)row - 1) * D + d] : 0.f;
  float v = prev * cw[2 * d] + cur * cw[2 * d + 1] + conv_b_l[rdir * D + d];
  float o = v * sigmoidf_(v);
  XCC[(size_t)g] = o;
  XCCbf[(size_t)g] = (__bf16)o;
}

// ---------------- dbc = xcc @ xproj_w.T (MFMA) -> DBC8 + BCb ----------------
__global__ __launch_bounds__(256) void k_xproj_mfma(
    const __bf16* __restrict__ XCCbf, const __bf16* __restrict__ Wbf,
    float* __restrict__ DBC8, float* __restrict__ BCb)
{
  __shared__ short As[128 * KS];
  __shared__ short Bs[64 * KS];
  int bx = blockIdx.x;
  int rdir = bx / MT128;
  int tile = bx % MT128;
  int tid = threadIdx.x;
  int m0 = tile * 128;
  const __bf16* Wb = Wbf + (size_t)rdir * 40 * 128;
  for (int q = tid; q < 128 * 16; q += 256) {
    int rr = q >> 4, g = q & 15;
    int m = m0 + rr;
    int4 v = make_int4(0, 0, 0, 0);
    if (m < BL) v = *(const int4*)(XCCbf + ((size_t)rdir * BL + m) * 128 + g * 8);
    *(int4*)&As[rr * KS + g * 8] = v;
  }
  for (int q = tid; q < 64 * 16; q += 256) {
    int rr = q >> 4, g = q & 15;
    int4 v = make_int4(0, 0, 0, 0);
    if (rr < 40) v = *(const int4*)(Wb + (size_t)rr * 128 + g * 8);
    *(int4*)&Bs[rr * KS + g * 8] = v;
  }
  __syncthreads();
  int wave = tid >> 6, lane = tid & 63, lm = lane & 15, lq = lane >> 4;
  f32x4 zero4 = {0.f, 0.f, 0.f, 0.f};
  f32x4 acc[2][4];
#pragma unroll
  for (int r = 0; r < 2; ++r)
#pragma unroll
    for (int c = 0; c < 4; ++c) acc[r][c] = zero4;
  for (int ks = 0; ks < 128; ks += 32) {
    bf16x8 af[2];
#pragma unroll
    for (int r = 0; r < 2; ++r)
      af[r] = *(const bf16x8*)&As[(wave * 32 + r * 16 + lm) * KS + ks + lq * 8];
#pragma unroll
    for (int c = 0; c < 3; ++c) {   // cols >= 48 are all zero/unused
      bf16x8 bfr = *(const bf16x8*)&Bs[(c * 16 + lm) * KS + ks + lq * 8];
#pragma unroll
      for (int r = 0; r < 2; ++r)
        acc[r][c] = __builtin_amdgcn_mfma_f32_16x16x32_bf16(af[r], bfr, acc[r][c], 0, 0, 0);
    }
  }
#pragma unroll
  for (int r = 0; r < 2; ++r) {
    int rowb = m0 + wave * 32 + r * 16 + lq * 4;
#pragma unroll
    for (int c = 0; c < 3; ++c) {
      int col = c * 16 + lm;
#pragma unroll
      for (int e = 0; e < 4; ++e) {
        int m = rowb + e;
        if (m >= BL) continue;
        size_t rowi = (size_t)rdir * BL + m;
        float v = acc[r][c][e];
        if (col < DTR) DBC8[rowi * 8 + col] = v;
        else if (col < DTR + 2 * DS) BCb[rowi * 32 + (col - DTR)] = v;
      }
    }
  }
}

// ---------------- dt = softplus(dbc8 @ dt_w.T + dt_b) ----------------
__global__ __launch_bounds__(256) void k_dt(
    const float* __restrict__ DBC8, const float* __restrict__ dt_w_l,
    const float* __restrict__ dt_b_l, float* __restrict__ DT)
{
  int g = blockIdx.x * 256 + threadIdx.x;    // 2*BL*D
  if (g >= 2 * BL * D) return;
  int d = g & 127;
  int row = g >> 7;
  int rdir = row / BL;
  const float* db = DBC8 + (size_t)row * 8;
  const float* dw = dt_w_l + (size_t)rdir * D * DTR + d * DTR;
  float a = dt_b_l[rdir * D + d];
#pragma unroll
  for (int j = 0; j < DTR; ++j) a += db[j] * dw[j];
  DT[(size_t)g] = (a > 20.f) ? a : log1pf(__expf(a));
}

// A_n check: A_init = log(1..16) broadcast -> A_n = -(n+1) exactly.
DEV bool an_is_linear(const float* An) {
  bool ok = true;
#pragma unroll
  for (int n = 0; n < DS; ++n)
    ok = ok && (fabsf(An[n] + (float)(n + 1)) < 1e-3f * (n + 1));
  return ok;
}

// ---------------- scan phase A ----------------
__global__ __launch_bounds__(128) void k_scanA(
    const float* __restrict__ DT, const float* __restrict__ XCC,
    const float* __restrict__ BCb, const float* __restrict__ Alog_l,
    float* __restrict__ HC, float* __restrict__ DTS)
{
  __shared__ float Bs[CT][DS];
  int blk = blockIdx.x;
  int c  = blk % NC;
  int rb = blk / NC;
  int rdir = rb / B;
  int d = threadIdx.x;
  int s0 = c * CT;
  int cnt = min(CT, L - s0);
  size_t rowbase = (size_t)rb * L + s0;
  for (int q = d; q < cnt * DS; q += 128)
    Bs[q >> 4][q & 15] = BCb[(rowbase + (q >> 4)) * 32 + (q & 15)];
  float An[DS];
  const float* Ab = Alog_l + (size_t)rdir * D * DS + (size_t)d * DS;
#pragma unroll
  for (int n = 0; n < DS; ++n) An[n] = -__expf(Ab[n]);
  bool fast = an_is_linear(An);
  __syncthreads();
  float h[DS];
#pragma unroll
  for (int n = 0; n < DS; ++n) h[n] = 0.f;
  float dts = 0.f;
  float dt_nx = DT[rowbase * D + d];
  float xc_nx = XCC[rowbase * D + d];
  if (fast) {
    for (int ss = 0; ss < cnt; ++ss) {
      float dt = dt_nx, xc = xc_nx;
      if (ss + 1 < cnt) {
        size_t ro = (rowbase + ss + 1) * D + d;
        dt_nx = DT[ro]; xc_nx = XCC[ro];
      }
      dts += dt;
      float e = dt * xc;
      float r = __expf(-dt);
      float p = r;
#pragma unroll
      for (int n = 0; n < DS; ++n) {
        h[n] = p * h[n] + e * Bs[ss][n];
        p *= r;
      }
    }
  } else {
    for (int ss = 0; ss < cnt; ++ss) {
      float dt = dt_nx, xc = xc_nx;
      if (ss + 1 < cnt) {
        size_t ro = (rowbase + ss + 1) * D + d;
        dt_nx = DT[ro]; xc_nx = XCC[ro];
      }
      dts += dt;
      float e = dt * xc;
#pragma unroll
      for (int n = 0; n < DS; ++n)
        h[n] = __expf(dt * An[n]) * h[n] + e * Bs[ss][n];
    }
  }
  float* hp = HC + ((size_t)blk * D + d) * DS;
#pragma unroll
  for (int n = 0; n < DS; ++n) hp[n] = h[n];
  DTS[(size_t)blk * D + d] = dts;
}

// ---------------- scan phase B ----------------
__global__ __launch_bounds__(128) void k_scanB(
    const float* __restrict__ HC, const float* __restrict__ DTS,
    const float* __restrict__ Alog_l, float* __restrict__ HIN)
{
  int rb = blockIdx.x;
  int rdir = rb / B;
  int d = threadIdx.x;
  float An[DS];
  const float* Ab = Alog_l + (size_t)rdir * D * DS + (size_t)d * DS;
#pragma unroll
  for (int n = 0; n < DS; ++n) An[n] = -__expf(Ab[n]);
  bool fast = an_is_linear(An);
  float h[DS];
#pragma unroll
  for (int n = 0; n < DS; ++n) h[n] = 0.f;
  size_t i0 = ((size_t)(rb * NC) * D + d) * DS;
  float dts_nx = DTS[(size_t)(rb * NC) * D + d];
  float4 h0 = *(const float4*)(HC + i0);
  float4 h1 = *(const float4*)(HC + i0 + 4);
  float4 h2 = *(const float4*)(HC + i0 + 8);
  float4 h3 = *(const float4*)(HC + i0 + 12);
  for (int c = 0; c < NC; ++c) {
    size_t idx = ((size_t)(rb * NC + c) * D + d) * DS;
    float* hin = HIN + idx;
    float hc[DS];
    hc[0]=h0.x; hc[1]=h0.y; hc[2]=h0.z; hc[3]=h0.w;
    hc[4]=h1.x; hc[5]=h1.y; hc[6]=h1.z; hc[7]=h1.w;
    hc[8]=h2.x; hc[9]=h2.y; hc[10]=h2.z; hc[11]=h2.w;
    hc[12]=h3.x; hc[13]=h3.y; hc[14]=h3.z; hc[15]=h3.w;
    float dts = dts_nx;
    if (c + 1 < NC) {
      size_t in2 = ((size_t)(rb * NC + c + 1) * D + d) * DS;
      dts_nx = DTS[(size_t)(rb * NC + c + 1) * D + d];
      h0 = *(const float4*)(HC + in2);
      h1 = *(const float4*)(HC + in2 + 4);
      h2 = *(const float4*)(HC + in2 + 8);
      h3 = *(const float4*)(HC + in2 + 12);
    }
#pragma unroll
    for (int n = 0; n < DS; ++n) hin[n] = h[n];
    if (fast) {
      float r = __expf(-dts);
      float p = r;
#pragma unroll
      for (int n = 0; n < DS; ++n) {
        h[n] = p * h[n] + hc[n];
        p *= r;
      }
    } else {
#pragma unroll
      for (int n = 0; n < DS; ++n)
        h[n] = __expf(dts * An[n]) * h[n] + hc[n];
    }
  }
}

// ---------------- scan phase C: emit y as bf16 into YMbf (m,[dir*128+d]) ----------------
__global__ __launch_bounds__(128) void k_scanC(
    const float* __restrict__ DT, const float* __restrict__ XCC,
    const float* __restrict__ BCb, const float* __restrict__ Zb,
    const float* __restrict__ HIN, const float* __restrict__ Alog_l,
    const float* __restrict__ Dp_l, __bf16* __restrict__ YMbf)
{
  __shared__ float Bs[CT][DS];
  __shared__ float Cs[CT][DS];
  int blk = blockIdx.x;
  int c  = blk % NC;
  int rb = blk / NC;
  int rdir = rb / B;
  int b = rb % B;
  int d = threadIdx.x;
  int s0 = c * CT;
  int cnt = min(CT, L - s0);
  size_t rowbase = (size_t)rb * L + s0;
  for (int q = d; q < cnt * 2 * DS; q += 128) {
    int ss = q >> 5, j = q & 31;
    float vv = BCb[(rowbase + ss) * 32 + j];
    if (j < DS) Bs[ss][j] = vv; else Cs[ss][j - DS] = vv;
  }
  float An[DS];
  const float* Ab = Alog_l + (size_t)rdir * D * DS + (size_t)d * DS;
#pragma unroll
  for (int n = 0; n < DS; ++n) An[n] = -__expf(Ab[n]);
  bool fast = an_is_linear(An);
  float h[DS];
  const float* hin = HIN + ((size_t)blk * D + d) * DS;
#pragma unroll
  for (int n = 0; n < DS; ++n) h[n] = hin[n];
  float Dpv = Dp_l[rdir * D + d];
  __syncthreads();
  float dt_nx = DT[rowbase * D + d];
  float xc_nx = XCC[rowbase * D + d];
  float z_nx  = Zb[rowbase * D + d];
  if (fast) {
    for (int ss = 0; ss < cnt; ++ss) {
      float dt = dt_nx, xc = xc_nx, z = z_nx;
      if (ss + 1 < cnt) {
        size_t ro = (rowbase + ss + 1) * D + d;
        dt_nx = DT[ro]; xc_nx = XCC[ro]; z_nx = Zb[ro];
      }
      float e = dt * xc;
      float r = __expf(-dt);
      float p = r;
      float y = 0.f;
#pragma unroll
      for (int n = 0; n < DS; ++n) {
        h[n] = p * h[n] + e * Bs[ss][n];
        y += h[n] * Cs[ss][n];
        p *= r;
      }
      y += xc * Dpv;
      y *= z * sigmoidf_(z);
      int s = s0 + ss;
      int tt = rdir ? (L - 1 - s) : s;
      YMbf[((size_t)b * L + tt) * 256 + rdir * 128 + d] = (__bf16)y;
    }
  } else {
    for (int ss = 0; ss < cnt; ++ss) {
      float dt = dt_nx, xc = xc_nx, z = z_nx;
      if (ss + 1 < cnt) {
        size_t ro = (rowbase + ss + 1) * D + d;
        dt_nx = DT[ro]; xc_nx = XCC[ro]; z_nx = Zb[ro];
      }
      float e = dt * xc;
      float y = 0.f;
#pragma unroll
      for (int n = 0; n < DS; ++n) {
        h[n] = __expf(dt * An[n]) * h[n] + e * Bs[ss][n];
        y += h[n] * Cs[ss][n];
      }
      y += xc * Dpv;
      y *= z * sigmoidf_(z);
      int s = s0 + ss;
      int tt = rdir ? (L - 1 - s) : s;
      YMbf[((size_t)b * L + tt) * 256 + rdir * 128 + d] = (__bf16)y;
    }
  }
}

// ---------------- out-proj (both dirs via K=256 concat), U += (MFMA) ----------------
__global__ __launch_bounds__(256) void k_outproj_mfma(
    const __bf16* __restrict__ YMbf, const __bf16* __restrict__ Wbf,
    float* __restrict__ U)
{
  __shared__ short As[128 * KS];
  __shared__ short Bs[64 * KS];
  int m0 = blockIdx.x * 128;
  int col0 = blockIdx.y * 64;
  int tid = threadIdx.x;
  int wave = tid >> 6, lane = tid & 63, lm = lane & 15, lq = lane >> 4;
  f32x4 zero4 = {0.f, 0.f, 0.f, 0.f};
  f32x4 acc[2][4];
#pragma unroll
  for (int r = 0; r < 2; ++r)
#pragma unroll
    for (int c = 0; c < 4; ++c) acc[r][c] = zero4;
  for (int kc = 0; kc < 2; ++kc) {
    if (kc) __syncthreads();
    for (int q = tid; q < 128 * 16; q += 256) {
      int rr = q >> 4, g = q & 15;
      int m = m0 + rr;
      int4 v = make_int4(0, 0, 0, 0);
      if (m < BL) v = *(const int4*)(YMbf + (size_t)m * 256 + kc * 128 + g * 8);
      *(int4*)&As[rr * KS + g * 8] = v;
    }
    for (int q = tid; q < 64 * 16; q += 256) {
      int rr = q >> 4, g = q & 15;
      int4 v = *(const int4*)(Wbf + (size_t)(col0 + rr) * 256 + kc * 128 + g * 8);
      *(int4*)&Bs[rr * KS + g * 8] = v;
    }
    __syncthreads();
    for (int ks = 0; ks < 128; ks += 32) {
      bf16x8 af[2];
#pragma unroll
      for (int r = 0; r < 2; ++r)
        af[r] = *(const bf16x8*)&As[(wave * 32 + r * 16 + lm) * KS + ks + lq * 8];
#pragma unroll
      for (int c = 0; c < 4; ++c) {
        bf16x8 bfr = *(const bf16x8*)&Bs[(c * 16 + lm) * KS + ks + lq * 8];
#pragma unroll
        for (int r = 0; r < 2; ++r)
          acc[r][c] = __builtin_amdgcn_mfma_f32_16x16x32_bf16(af[r], bfr, acc[r][c], 0, 0, 0);
      }
    }
  }
#pragma unroll
  for (int r = 0; r < 2; ++r) {
    int rowb = m0 + wave * 32 + r * 16 + lq * 4;
#pragma unroll
    for (int c = 0; c < 4; ++c) {
      int col = col0 + c * 16 + lm;
#pragma unroll
      for (int e = 0; e < 4; ++e) {
        int m = rowb + e;
        if (m < BL) U[(size_t)m * 128 + col] += acc[r][c][e];
      }
    }
  }
}

// ---------------- LN1 -> XR fp32 + XRbf bf16 ----------------
__global__ __launch_bounds__(256) void k_ln1(
    const float* __restrict__ U, const float* __restrict__ g,
    const float* __restrict__ be, float* __restrict__ XR,
    __bf16* __restrict__ XRbf)
{
  int row = blockIdx.x * 4 + (threadIdx.x >> 6);
  int lane = threadIdx.x & 63;
  if (row >= BL) return;
  const float* ur = U + (size_t)row * D;
  float x0 = ur[lane], x1 = ur[lane + 64];
  float mean = wsum(x0 + x1) * (1.f / D);
  float d0 = x0 - mean, d1 = x1 - mean;
  float var = wsum(d0 * d0 + d1 * d1) * (1.f / D);
  float inv = rsqrtf(var + 1e-5f);
  float o0 = d0 * inv * g[lane] + be[lane];
  float o1 = d1 * inv * g[lane + 64] + be[lane + 64];
  XR[(size_t)row * D + lane]        = o0;
  XR[(size_t)row * D + lane + 64]   = o1;
  XRbf[(size_t)row * D + lane]      = (__bf16)o0;
  XRbf[(size_t)row * D + lane + 64] = (__bf16)o1;
}

// ---------------- FFN1: H = relu(XR @ w1.T + b1) -> bf16 (MFMA) ----------------
__global__ __launch_bounds__(256) void k_ffn1_mfma(
    const __bf16* __restrict__ XRbf, const __bf16* __restrict__ w1bf,
    const float* __restrict__ b1, __bf16* __restrict__ Hbf)
{
  __shared__ short As[128 * KS];
  __shared__ short Bs[64 * KS];
  int m0 = blockIdx.x * 128;
  int col0 = blockIdx.y * 64;
  int tid = threadIdx.x;
  for (int q = tid; q < 128 * 16; q += 256) {
    int rr = q >> 4, g = q & 15;
    int m = m0 + rr;
    int4 v = make_int4(0, 0, 0, 0);
    if (m < BL) v = *(const int4*)(XRbf + (size_t)m * 128 + g * 8);
    *(int4*)&As[rr * KS + g * 8] = v;
  }
  for (int q = tid; q < 64 * 16; q += 256) {
    int rr = q >> 4, g = q & 15;
    int4 v = *(const int4*)(w1bf + (size_t)(col0 + rr) * 128 + g * 8);
    *(int4*)&Bs[rr * KS + g * 8] = v;
  }
  __syncthreads();
  int wave = tid >> 6, lane = tid & 63, lm = lane & 15, lq = lane >> 4;
  f32x4 zero4 = {0.f, 0.f, 0.f, 0.f};
  f32x4 acc[2][4];
#pragma unroll
  for (int r = 0; r < 2; ++r)
#pragma unroll
    for (int c = 0; c < 4; ++c) acc[r][c] = zero4;
  for (int ks = 0; ks < 128; ks += 32) {
    bf16x8 af[2];
#pragma unroll
    for (int r = 0; r < 2; ++r)
      af[r] = *(const bf16x8*)&As[(wave * 32 + r * 16 + lm) * KS + ks + lq * 8];
#pragma unroll
    for (int c = 0; c < 4; ++c) {
      bf16x8 bfr = *(const bf16x8*)&Bs[(c * 16 + lm) * KS + ks + lq * 8];
#pragma unroll
      for (int r = 0; r < 2; ++r)
        acc[r][c] = __builtin_amdgcn_mfma_f32_16x16x32_bf16(af[r], bfr, acc[r][c], 0, 0, 0);
    }
  }
#pragma unroll
  for (int r = 0; r < 2; ++r) {
    int rowb = m0 + wave * 32 + r * 16 + lq * 4;
#pragma unroll
    for (int c = 0; c < 4; ++c) {
      int col = col0 + c * 16 + lm;
      float bb = b1[col];
#pragma unroll
      for (int e = 0; e < 4; ++e) {
        int m = rowb + e;
        if (m < BL)
          Hbf[(size_t)m * 256 + col] = (__bf16)fmaxf(acc[r][c][e] + bb, 0.f);
      }
    }
  }
}

// ---------------- FFN2: (H @ w2.T + b2 + XR) -> LN2 -> U fp32 + Ubf (MFMA) ----------------
__global__ __launch_bounds__(256) void k_ffn2_mfma(
    const __bf16* __restrict__ Hbf, const __bf16* __restrict__ w2bf,
    const float* __restrict__ b2, const float* __restrict__ XR,
    const float* __restrict__ g2, const float* __restrict__ be2,
    float* __restrict__ U, __bf16* __restrict__ Ubf)
{
  __shared__ short As[64 * KS];
  __shared__ short Bs[128 * KS];
  int m0 = blockIdx.x * 64;
  int tid = threadIdx.x;
  int wave = tid >> 6, lane = tid & 63, lm = lane & 15, lq = lane >> 4;
  f32x4 zero4 = {0.f, 0.f, 0.f, 0.f};
  f32x4 acc[8];
#pragma unroll
  for (int c = 0; c < 8; ++c) acc[c] = zero4;
  for (int kc = 0; kc < 2; ++kc) {
    if (kc) __syncthreads();
    for (int q = tid; q < 64 * 16; q += 256) {
      int rr = q >> 4, g = q & 15;
      int m = m0 + rr;
      int4 v = make_int4(0, 0, 0, 0);
      if (m < BL) v = *(const int4*)(Hbf + (size_t)m * 256 + kc * 128 + g * 8);
      *(int4*)&As[rr * KS + g * 8] = v;
    }
    for (int q = tid; q < 128 * 16; q += 256) {
      int rr = q >> 4, g = q & 15;
      int4 v = *(const int4*)(w2bf + (size_t)rr * 256 + kc * 128 + g * 8);
      *(int4*)&Bs[rr * KS + g * 8] = v;
    }
    __syncthreads();
    for (int ks = 0; ks < 128; ks += 32) {
      bf16x8 af = *(const bf16x8*)&As[(wave * 16 + lm) * KS + ks + lq * 8];
#pragma unroll
      for (int c = 0; c < 8; ++c) {
        bf16x8 bfr = *(const bf16x8*)&Bs[(c * 16 + lm) * KS + ks + lq * 8];
        acc[c] = __builtin_amdgcn_mfma_f32_16x16x32_bf16(af, bfr, acc[c], 0, 0, 0);
      }
    }
  }
  float b2c[8], g2c[8], be2c[8];
#pragma unroll
  for (int c = 0; c < 8; ++c) {
    int col = c * 16 + lm;
    b2c[c] = b2[col]; g2c[c] = g2[col]; be2c[c] = be2[col];
  }
#pragma unroll
  for (int r = 0; r < 4; ++r) {
    int row = m0 + wave * 16 + lq * 4 + r;
    bool valid = row < BL;
    float os[8];
    float sum = 0.f;
#pragma unroll
    for (int c = 0; c < 8; ++c) {
      int col = c * 16 + lm;
      float xr = valid ? XR[(size_t)row * 128 + col] : 0.f;
      os[c] = acc[c][r] + b2c[c] + xr;
      sum += os[c];
    }
#pragma unroll
    for (int mm = 1; mm < 16; mm <<= 1) sum += __shfl_xor(sum, mm, 64);
    float mean = sum * (1.f / 128.f);
    float qv = 0.f;
#pragma unroll
    for (int c = 0; c < 8; ++c) { float dv = os[c] - mean; qv += dv * dv; }
#pragma unroll
    for (int mm = 1; mm < 16; mm <<= 1) qv += __shfl_xor(qv, mm, 64);
    float inv = rsqrtf(qv * (1.f / 128.f) + 1e-5f);
    if (valid) {
#pragma unroll
      for (int c = 0; c < 8; ++c) {
        int col = c * 16 + lm;
        float o = (os[c] - mean) * inv * g2c[c] + be2c[c];
        U[(size_t)row * 128 + col] = o;
        Ubf[(size_t)row * 128 + col] = (__bf16)o;
      }
    }
  }
}

// ---------------- final LN + slice + transpose -> out (B,N,D,P) ----------------
__global__ __launch_bounds__(256) void k_lnf_out(
    const float* __restrict__ U, const float* __restrict__ g,
    const float* __restrict__ be, float* __restrict__ out)
{
  int gg = blockIdx.x * 4 + (threadIdx.x >> 6);   // [0, B*2048)
  int lane = threadIdx.x & 63;
  int b = gg >> 11, t = gg & 2047;
  const float* ur = U + ((size_t)b * L + t) * D;
  float x0 = ur[lane], x1 = ur[lane + 64];
  float mean = wsum(x0 + x1) * (1.f / D);
  float d0 = x0 - mean, d1 = x1 - mean;
  float var = wsum(d0 * d0 + d1 * d1) * (1.f / D);
  float inv = rsqrtf(var + 1e-5f);
  float o0 = d0 * inv * g[lane] + be[lane];
  float o1 = d1 * inv * g[lane + 64] + be[lane + 64];
  int n = t >> 7, p = t & 127;
  size_t obase = (((size_t)b * N + n) * D) * P + p;
  out[obase + (size_t)lane * P] = o0;
  out[obase + (size_t)(lane + 64) * P] = o1;
}

extern "C" void kernel_launch(void* const* d_in, const int* in_sizes, int n_in,
                              void* d_out, int out_size, void* d_ws, size_t ws_size,
                              hipStream_t stream)
{
  (void)in_sizes; (void)n_in; (void)out_size; (void)ws_size;
  const float* x       = (const float*)d_in[0];
  const float* view    = (const float*)d_in[1];
  const float* wp_w    = (const float*)d_in[2];
  const float* wp_b    = (const float*)d_in[3];
  const float* m_in_w  = (const float*)d_in[4];
  const float* m_conv_w= (const float*)d_in[5];
  const float* m_conv_b= (const float*)d_in[6];
  const float* m_xproj = (const float*)d_in[7];
  const float* m_dt_w  = (const float*)d_in[8];
  const float* m_dt_b  = (const float*)d_in[9];
  const float* m_Alog  = (const float*)d_in[10];
  const float* m_Dp    = (const float*)d_in[11];
  const float* m_out_w = (const float*)d_in[12];
  const float* ffn_w1  = (const float*)d_in[13];
  const float* ffn_b1  = (const float*)d_in[14];
  const float* ffn_w2  = (const float*)d_in[15];
  const float* ffn_b2  = (const float*)d_in[16];
  const float* ln1_g   = (const float*)d_in[17];
  const float* ln1_b   = (const float*)d_in[18];
  const float* ln2_g   = (const float*)d_in[19];
  const float* ln2_b   = (const float*)d_in[20];
  const float* lnf_g   = (const float*)d_in[21];
  const float* lnf_b   = (const float*)d_in[22];
  float* out = (float*)d_out;

  float* W = (float*)d_ws;
  size_t off = 0;
  auto alloc = [&](size_t nfl) { float* p = W + off; off += (nfl + 3) & ~(size_t)3; return p; };
  float* U    = alloc((size_t)BL * D);
  float* XCP  = alloc((size_t)2 * BL * D);   // also hosts Hbf + YMbf (bf16) later in layer
  float* XCC  = alloc((size_t)2 * BL * D);
  float* Zb   = alloc((size_t)2 * BL * D);   // first half also hosts XRbf after scanC
  float* DTb  = alloc((size_t)2 * BL * D);   // first half also hosts XR after scanC
  float* BCb  = alloc((size_t)2 * BL * 2 * DS);
  float* DBC8 = alloc((size_t)2 * BL * DTR);
  float* HC   = alloc((size_t)2 * B * NC * D * DS);
  float* DTS  = alloc((size_t)2 * B * NC * D);
  float* HIN  = alloc((size_t)2 * B * NC * D * DS);  // also hosts XCCbf (steps 2-3)
  float* Ubf_f   = alloc((size_t)BL * D / 2);
  float* inw_f   = alloc(131072 / 2);
  float* xpw_f   = alloc(20480 / 2);
  float* outw_f  = alloc(65536 / 2);
  float* w1_f    = alloc(65536 / 2);
  float* w2_f    = alloc(65536 / 2);

  __bf16* Ubf    = (__bf16*)Ubf_f;
  __bf16* inw_bf = (__bf16*)inw_f;
  __bf16* xpw_bf = (__bf16*)xpw_f;
  __bf16* outw_bf= (__bf16*)outw_f;
  __bf16* w1_bf  = (__bf16*)w1_f;
  __bf16* w2_bf  = (__bf16*)w2_f;
  __bf16* Hbf    = (__bf16*)XCP;                         // BL*256 bf16
  __bf16* YMbf   = (__bf16*)(XCP + (size_t)BL * 128);    // BL*256 bf16
  __bf16* XCCbf  = (__bf16*)HIN;                         // 2*BL*128 bf16 (fits: HIN is 2.13M fl)
  float*  XR     = DTb;                                  // BL*128 fp32 (DTb dead post-scan)
  __bf16* XRbf   = (__bf16*)Zb;                          // BL*128 bf16 (Zb dead post-scan)

  k_prep<<<1360, 256, 0, stream>>>(m_in_w, m_xproj, m_out_w, ffn_w1, ffn_w2,
                                   inw_bf, xpw_bf, outw_bf, w1_bf, w2_bf);
  k_embed<<<(BL * D + 255) / 256, 256, 0, stream>>>(x, view, wp_w, wp_b, U, Ubf);

  for (int l = 0; l < EL; ++l) {
    const float* conv_w_l = m_conv_w + (size_t)l * 2 * D * 2;
    const float* conv_b_l = m_conv_b + (size_t)l * 2 * D;
    const float* dt_w_l   = m_dt_w   + (size_t)l * 2 * D * DTR;
    const float* dt_b_l   = m_dt_b   + (size_t)l * 2 * D;
    const float* Alog_l   = m_Alog   + (size_t)l * 2 * D * DS;
    const float* Dp_l     = m_Dp     + (size_t)l * 2 * D;

    k_xz_mfma   <<<dim3(2 * MT128, 4), 256, 0, stream>>>(Ubf, inw_bf + (size_t)l * 2 * 256 * 128, XCP, Zb);
    k_conv      <<<(2 * BL * D) / 256, 256, 0, stream>>>(XCP, conv_w_l, conv_b_l, XCC, XCCbf);
    k_xproj_mfma<<<dim3(2 * MT128, 1), 256, 0, stream>>>(XCCbf, xpw_bf + (size_t)l * 2 * 40 * 128, DBC8, BCb);
    k_dt        <<<(2 * BL * D) / 256, 256, 0, stream>>>(DBC8, dt_w_l, dt_b_l, DTb);
    k_scanA     <<<2 * B * NC, 128, 0, stream>>>(DTb, XCC, BCb, Alog_l, HC, DTS);
    k_scanB     <<<2 * B, 128, 0, stream>>>(HC, DTS, Alog_l, HIN);
    k_scanC     <<<2 * B * NC, 128, 0, stream>>>(DTb, XCC, BCb, Zb, HIN, Alog_l, Dp_l, YMbf);
    k_outproj_mfma<<<dim3(MT128, 2), 256, 0, stream>>>(YMbf, outw_bf + (size_t)l * 128 * 256, U);
    k_ln1       <<<(BL + 3) / 4, 256, 0, stream>>>(U, ln1_g + l * D, ln1_b + l * D, XR, XRbf);
    k_ffn1_mfma <<<dim3(MT128, 4), 256, 0, stream>>>(XRbf, w1_bf + (size_t)l * 256 * 128, ffn_b1 + l * DFF, Hbf);
    k_ffn2_mfma <<<dim3(MT64, 1), 256, 0, stream>>>(Hbf, w2_bf + (size_t)l * 128 * 256, ffn_b2 + l * D, XR,
                                                    ln2_g + l * D, ln2_b + l * D, U, Ubf);
  }
  k_lnf_out<<<(B * N * P) / 4, 256, 0, stream>>>(U, lnf_g, lnf_b, out);
}